// Round 1
// baseline (4223.574 us; speedup 1.0000x reference)
//
#include <hip/hip_runtime.h>
#include <hip/hip_bf16.h>
#include <math.h>

#define Wd 128
#define Hd 128
#define HW 16384
#define CH 64
#define TT 8
#define NEGS 0.2f

// Generic 3x3 conv, pad=1, stride=1, 64->64 channels, one frame per blockIdx.z.
// IN_X:    input tensor is x in (B,C,T,H,W) layout (frame f=(b,t) strided)
// SHIFTMUL: input is shifted(input)*input (S2-MLP 4-group spatial shift, s=4)
// LRELU:   leaky-relu(0.2) applied after bias
// RESID_X: add x (B,C,T,H,W layout) residual to output
// FUSE1x1: staged input = wk1 @ in + bk1 (1x1 conv fused into staging)
template<bool IN_X, bool SHIFTMUL, bool LRELU, bool RESID_X, bool FUSE1x1>
__global__ __launch_bounds__(256) void conv3x3_k(
    const float* __restrict__ in, const float* __restrict__ wgt,
    const float* __restrict__ bias, const float* __restrict__ xres,
    const float* __restrict__ w1x1, const float* __restrict__ b1x1,
    float* __restrict__ out)
{
  const int f = blockIdx.z;
  const int h0 = blockIdx.y * 8;
  const int w0 = blockIdx.x * 32;
  const int tid = threadIdx.x;
  const int tx = tid & 31, ty = tid >> 5;

  __shared__ float tile[8 * 340];   // 8 cin x 10 rows x 34 cols

  float acc[64];
#pragma unroll
  for (int i = 0; i < 64; ++i) acc[i] = 0.f;

  int inBase, cstr;
  if (IN_X) { int b = f >> 3, t = f & 7; inBase = (b * 512 + t) * HW; cstr = TT * HW; }
  else      { inBase = f * CH * HW; cstr = HW; }

#pragma unroll 1
  for (int cb = 0; cb < 64; cb += 8) {
    __syncthreads();
    if (FUSE1x1) {
#pragma unroll 1
      for (int ci = 0; ci < 8; ++ci) {
        const int c = cb + ci;
#pragma unroll 1
        for (int e2 = tid; e2 < 340; e2 += 256) {
          int r = e2 / 34; int cc2 = e2 - r * 34;
          int gh = h0 + r - 1, gw = w0 + cc2 - 1;
          float v = 0.f;
          if (gh >= 0 && gh < Hd && gw >= 0 && gw < Wd) {
            v = b1x1[c];
            int off = inBase + gh * Wd + gw;
#pragma unroll
            for (int cp = 0; cp < 64; ++cp)
              v = fmaf(in[off + cp * cstr], w1x1[c * 64 + cp], v);
          }
          tile[ci * 340 + e2] = v;
        }
      }
    } else {
#pragma unroll 1
      for (int e = tid; e < 8 * 340; e += 256) {
        int ci = e / 340; int rem = e - ci * 340;
        int r = rem / 34; int cc2 = rem - r * 34;
        int gh = h0 + r - 1, gw = w0 + cc2 - 1;
        const int c = cb + ci;
        float v = 0.f;
        if (gh >= 0 && gh < Hd && gw >= 0 && gw < Wd) {
          v = in[inBase + c * cstr + gh * Wd + gw];
          if (SHIFTMUL) {
            int g = c >> 4;           // 16-channel shift groups
            int ph = gh, pw = gw;
            if (g == 0) pw -= 4; else if (g == 1) pw += 4;
            else if (g == 2) ph -= 4; else ph += 4;
            float pv = 0.f;
            if (ph >= 0 && ph < Hd && pw >= 0 && pw < Wd)
              pv = in[inBase + c * cstr + ph * Wd + pw];
            v *= pv;
          }
        }
        tile[e] = v;
      }
    }
    __syncthreads();

#pragma unroll 1
    for (int ci = 0; ci < 8; ++ci) {
      const float* tp = &tile[ci * 340 + ty * 34 + tx];
      float v00 = tp[0],  v01 = tp[1],  v02 = tp[2];
      float v10 = tp[34], v11 = tp[35], v12 = tp[36];
      float v20 = tp[68], v21 = tp[69], v22 = tp[70];
      const int cin = cb + ci;
#pragma unroll
      for (int co = 0; co < 64; ++co) {
        const float* wp = &wgt[(co * 64 + cin) * 9];  // uniform -> s_load
        float a = acc[co];
        a = fmaf(v00, wp[0], a);
        a = fmaf(v01, wp[1], a);
        a = fmaf(v02, wp[2], a);
        a = fmaf(v10, wp[3], a);
        a = fmaf(v11, wp[4], a);
        a = fmaf(v12, wp[5], a);
        a = fmaf(v20, wp[6], a);
        a = fmaf(v21, wp[7], a);
        a = fmaf(v22, wp[8], a);
        acc[co] = a;
      }
    }
  }

  const int oh = h0 + ty, ow = w0 + tx;
  const int outBase = f * CH * HW + oh * Wd + ow;
  int xBase = 0;
  if (RESID_X) { int b = f >> 3, t = f & 7; xBase = (b * 512 + t) * HW + oh * Wd + ow; }
#pragma unroll
  for (int co = 0; co < 64; ++co) {
    float r = acc[co] + bias[co];
    if (LRELU) r = (r >= 0.f) ? r : NEGS * r;
    if (RESID_X) r += xres[xBase + co * (TT * HW)];
    out[outBase + co * HW] = r;
  }
}

// 3x3 conv, stride 2, pad 1, 64 -> 9 channels (scores). Output (16,9,64,64).
__global__ __launch_bounds__(256) void convs2_k(
    const float* __restrict__ in, const float* __restrict__ wgt,
    const float* __restrict__ bias, float* __restrict__ out)
{
  const int f = blockIdx.y;
  const int idx = blockIdx.x * 256 + threadIdx.x;   // 4096 out pixels
  const int wo = idx & 63, ho = idx >> 6;
  const int inBase = f * CH * HW;
  const int hc = 2 * ho - 1, wc = 2 * wo - 1;
  float acc[9];
#pragma unroll
  for (int i = 0; i < 9; ++i) acc[i] = 0.f;
#pragma unroll 1
  for (int ci = 0; ci < 64; ++ci) {
    float v[9];
#pragma unroll
    for (int di = 0; di < 3; ++di)
#pragma unroll
      for (int dj = 0; dj < 3; ++dj) {
        int h = hc + di, w = wc + dj;
        v[di * 3 + dj] = (h >= 0 && h < Hd && w >= 0 && w < Wd)
            ? in[inBase + ci * HW + h * Wd + w] : 0.f;
      }
#pragma unroll
    for (int kk = 0; kk < 9; ++kk) {
      const float* wp = &wgt[(kk * 64 + ci) * 9];
      float a = acc[kk];
#pragma unroll
      for (int q = 0; q < 9; ++q) a = fmaf(v[q], wp[q], a);
      acc[kk] = a;
    }
  }
  const int oBase = f * 9 * 4096 + ho * 64 + wo;
#pragma unroll
  for (int kk = 0; kk < 9; ++kk) out[oBase + kk * 4096] = acc[kk] + bias[kk];
}

// softmax over 72 = T*K*K per (b,ho,wo). scores (16,9,64,64) -> wout (b,pix,72)
__global__ __launch_bounds__(256) void softmax_k(
    const float* __restrict__ sc, float* __restrict__ wout)
{
  const int idx = blockIdx.x * 256 + threadIdx.x;   // 8192 = 2*64*64
  const int b = idx >> 12, pix = idx & 4095;
  float v[72];
  float mx = -1e30f;
#pragma unroll
  for (int t = 0; t < 8; ++t)
#pragma unroll
    for (int kk = 0; kk < 9; ++kk) {
      float s = sc[((b * 8 + t) * 9 + kk) * 4096 + pix];
      v[t * 9 + kk] = s;
      mx = fmaxf(mx, s);
    }
  float sum = 0.f;
#pragma unroll
  for (int i = 0; i < 72; ++i) { v[i] = __expf(v[i] - mx); sum += v[i]; }
  float inv = 1.f / sum;
#pragma unroll
  for (int i = 0; i < 72; ++i) wout[idx * 72 + i] = v[i] * inv;
}

// weighted patch reduce: out[b,c,ho,wo] = sum_{t,i,j} w[b,ho,wo,t,i,j]*x5[b,c,t,h,w]
// x5 in frame-major (16,64,128,128); replicate-pad indexing h=clamp(2ho+i-1).
__global__ __launch_bounds__(256) void gather_k(
    const float* __restrict__ x5, const float* __restrict__ wts,
    float* __restrict__ out)
{
  const int cgrp = blockIdx.x;   // 8 channel groups of 8
  const int ho = blockIdx.y;     // 64
  const int b = blockIdx.z;      // 2
  __shared__ float wl[64 * 73];  // pad 72->73: stride 73 % 32 coprime -> no conflicts
  const float* wsrc = &wts[(b * 4096 + ho * 64) * 72];
  for (int e = threadIdx.x; e < 64 * 72; e += 256) {
    int wo = e / 72, k = e - wo * 72;
    wl[wo * 73 + k] = wsrc[e];
  }
  __syncthreads();
  const int wo = threadIdx.x & 63;
  const int sub = threadIdx.x >> 6;   // 0..3
  const int hc = 2 * ho - 1, wc = 2 * wo - 1;
#pragma unroll
  for (int cc2 = 0; cc2 < 2; ++cc2) {
    const int c = cgrp * 8 + sub * 2 + cc2;
    float acc = 0.f;
#pragma unroll 1
    for (int t = 0; t < 8; ++t) {
      const int base = ((b * 8 + t) * 64 + c) * HW;
      const float* wrow = &wl[wo * 73 + t * 9];
#pragma unroll
      for (int di = 0; di < 3; ++di) {
        int h = min(max(hc + di, 0), 127);
#pragma unroll
        for (int dj = 0; dj < 3; ++dj) {
          int w = min(max(wc + dj, 0), 127);
          acc = fmaf(x5[base + h * Wd + w], wrow[di * 3 + dj], acc);
        }
      }
    }
    out[((b * 64 + c) * 64 + ho) * 64 + wo] = acc;
  }
}

extern "C" void kernel_launch(void* const* d_in, const int* in_sizes, int n_in,
                              void* d_out, int out_size, void* d_ws, size_t ws_size,
                              hipStream_t stream)
{
  const float* x   = (const float*)d_in[0];
  const float* w1  = (const float*)d_in[1];
  const float* b1  = (const float*)d_in[2];
  const float* w2  = (const float*)d_in[3];
  const float* b2  = (const float*)d_in[4];
  const float* wk1 = (const float*)d_in[5];
  const float* bk1 = (const float*)d_in[6];
  const float* wk2 = (const float*)d_in[7];
  const float* bk2 = (const float*)d_in[8];
  const float* wk3 = (const float*)d_in[9];
  const float* bk3 = (const float*)d_in[10];
  float* outp = (float*)d_out;

  char* ws = (char*)d_ws;
  float* A      = (float*)ws;                            // 64 MB: x5 (frame-major)
  float* Bf     = (float*)(ws + 67108864);               // 64 MB: res1, later kf2
  float* scores = (float*)(ws + 134217728);              // 2.25 MB
  float* wbuf   = (float*)(ws + 134217728 + 2359296);    // 2.25 MB
  (void)ws_size; (void)in_sizes; (void)n_in; (void)out_size;

  dim3 cgrid(4, 16, 16);   // 32w x 8h tiles, 16 frames
  // 1: res1 = lrelu(conv(xf, w1) + b1)                       -> Bf
  conv3x3_k<true,  false, true,  false, false><<<cgrid, 256, 0, stream>>>(
      x, w1, b1, nullptr, nullptr, nullptr, Bf);
  // 2: x5 = x + conv(shift(res1)*res1, w2) + b2              -> A
  conv3x3_k<false, true,  false, true,  false><<<cgrid, 256, 0, stream>>>(
      Bf, w2, b2, x, nullptr, nullptr, A);
  // 3: kf2 = lrelu(conv(wk1@x5 + bk1, wk2) + bk2)            -> Bf (1x1 fused)
  conv3x3_k<false, false, true,  false, true ><<<cgrid, 256, 0, stream>>>(
      A, wk2, bk2, nullptr, wk1, bk1, Bf);
  // 4: scores = conv_s2(kf2, wk3) + bk3                      -> scores
  convs2_k<<<dim3(16, 16), 256, 0, stream>>>(Bf, wk3, bk3, scores);
  // 5: softmax over 72
  softmax_k<<<dim3(32), 256, 0, stream>>>(scores, wbuf);
  // 6: weighted gather reduce
  gather_k<<<dim3(8, 64, 2), 256, 0, stream>>>(A, wbuf, outp);
}

// Round 2
// 3232.062 us; speedup vs baseline: 1.3068x; 1.3068x over previous
//
#include <hip/hip_runtime.h>
#include <hip/hip_bf16.h>
#include <math.h>

#define Wd 128
#define Hd 128
#define HW 16384
#define CH 64
#define TT 8
#define NEGS 0.2f

// 3x3 conv, pad=1, stride=1, 64->64 ch, one frame per blockIdx.z.
// Block: 1024 threads = 256 pixels (32w x 8h) x 4 cout-groups of 16.
// acc[16] per thread -> no spill (R0 lesson: acc[64] went to scratch).
template<bool IN_X, bool SHIFTMUL, bool LRELU, bool RESID_X>
__global__ __launch_bounds__(1024) void conv3x3_k(
    const float* __restrict__ in, const float* __restrict__ wgt,
    const float* __restrict__ bias, const float* __restrict__ xres,
    float* __restrict__ out)
{
  const int f = blockIdx.z;
  const int h0 = blockIdx.y * 8;
  const int w0 = blockIdx.x * 32;
  const int tid = threadIdx.x;
  const int p = tid & 255;          // pixel within 32x8 tile
  const int cg = tid >> 8;          // cout group 0..3 (wave-uniform)
  const int px = p & 31, py = p >> 5;

  __shared__ float tile[8 * 340];   // 8 cin x 10 rows x 34 cols

  float acc[16];
#pragma unroll
  for (int i = 0; i < 16; ++i) acc[i] = 0.f;

  int inBase, cstr;
  if (IN_X) { int b = f >> 3, t = f & 7; inBase = (b * 512 + t) * HW; cstr = TT * HW; }
  else      { inBase = f * CH * HW; cstr = HW; }

#pragma unroll 1
  for (int cb = 0; cb < 64; cb += 8) {
    __syncthreads();
#pragma unroll 1
    for (int e = tid; e < 8 * 340; e += 1024) {
      int ci = e / 340; int rem = e - ci * 340;
      int r = rem / 34; int cc2 = rem - r * 34;
      int gh = h0 + r - 1, gw = w0 + cc2 - 1;
      const int c = cb + ci;
      float v = 0.f;
      if (gh >= 0 && gh < Hd && gw >= 0 && gw < Wd) {
        v = in[inBase + c * cstr + gh * Wd + gw];
        if (SHIFTMUL) {
          int g = c >> 4;           // 16-channel shift groups
          int ph = gh, pw = gw;
          if (g == 0) pw -= 4; else if (g == 1) pw += 4;
          else if (g == 2) ph -= 4; else ph += 4;
          float pv = 0.f;
          if (ph >= 0 && ph < Hd && pw >= 0 && pw < Wd)
            pv = in[inBase + c * cstr + ph * Wd + pw];
          v *= pv;
        }
      }
      tile[e] = v;
    }
    __syncthreads();

#pragma unroll 1
    for (int ci = 0; ci < 8; ++ci) {
      const float* tp = &tile[ci * 340 + py * 34 + px];
      float v00 = tp[0],  v01 = tp[1],  v02 = tp[2];
      float v10 = tp[34], v11 = tp[35], v12 = tp[36];
      float v20 = tp[68], v21 = tp[69], v22 = tp[70];
      const int cin = cb + ci;
      const float* wb = &wgt[(cg * 16 * 64 + cin) * 9];   // wave-uniform
#pragma unroll
      for (int co = 0; co < 16; ++co) {
        const float* wp = wb + co * 576;                  // (co*64)*9
        float a = acc[co];
        a = fmaf(v00, wp[0], a);
        a = fmaf(v01, wp[1], a);
        a = fmaf(v02, wp[2], a);
        a = fmaf(v10, wp[3], a);
        a = fmaf(v11, wp[4], a);
        a = fmaf(v12, wp[5], a);
        a = fmaf(v20, wp[6], a);
        a = fmaf(v21, wp[7], a);
        a = fmaf(v22, wp[8], a);
        acc[co] = a;
      }
    }
  }

  const int oh = h0 + py, ow = w0 + px;
  const int outBase = f * CH * HW + oh * Wd + ow;
  int xBase = 0;
  if (RESID_X) { int b = f >> 3, t = f & 7; xBase = (b * 512 + t) * HW + oh * Wd + ow; }
#pragma unroll
  for (int co = 0; co < 16; ++co) {
    const int c = cg * 16 + co;
    float r = acc[co] + bias[c];
    if (LRELU) r = (r >= 0.f) ? r : NEGS * r;
    if (RESID_X) r += xres[xBase + c * (TT * HW)];
    out[outBase + c * HW] = r;
  }
}

// 1x1 conv (k = wk1 @ x5 + bk1), frame-major in/out. One pixel per thread,
// all 64 inputs held in registers, 4 x (64x16) FMA passes.
__global__ __launch_bounds__(256) void conv1x1_k(
    const float* __restrict__ in, const float* __restrict__ w,
    const float* __restrict__ b, float* __restrict__ out)
{
  const int f = blockIdx.y;
  const int pix = blockIdx.x * 256 + threadIdx.x;
  const int base = f * CH * HW + pix;
  float v[64];
#pragma unroll
  for (int c = 0; c < 64; ++c) v[c] = in[base + c * HW];
#pragma unroll 1
  for (int cg = 0; cg < 4; ++cg) {
    float acc[16];
#pragma unroll
    for (int o = 0; o < 16; ++o) acc[o] = b[cg * 16 + o];
#pragma unroll
    for (int c = 0; c < 64; ++c) {
      const float* wp = &w[cg * 16 * 64 + c];
#pragma unroll
      for (int o = 0; o < 16; ++o)
        acc[o] = fmaf(v[c], wp[o * 64], acc[o]);
    }
#pragma unroll
    for (int o = 0; o < 16; ++o)
      out[base + (cg * 16 + o) * HW] = acc[o];
  }
}

// 3x3 conv, stride 2, pad 1, 64 -> 9 channels (scores). Output (16,9,64,64).
__global__ __launch_bounds__(256) void convs2_k(
    const float* __restrict__ in, const float* __restrict__ wgt,
    const float* __restrict__ bias, float* __restrict__ out)
{
  const int f = blockIdx.y;
  const int idx = blockIdx.x * 256 + threadIdx.x;   // 4096 out pixels
  const int wo = idx & 63, ho = idx >> 6;
  const int inBase = f * CH * HW;
  const int hc = 2 * ho - 1, wc = 2 * wo - 1;
  float acc[9];
#pragma unroll
  for (int i = 0; i < 9; ++i) acc[i] = 0.f;
#pragma unroll 1
  for (int ci = 0; ci < 64; ++ci) {
    float v[9];
#pragma unroll
    for (int di = 0; di < 3; ++di)
#pragma unroll
      for (int dj = 0; dj < 3; ++dj) {
        int h = hc + di, w = wc + dj;
        v[di * 3 + dj] = (h >= 0 && h < Hd && w >= 0 && w < Wd)
            ? in[inBase + ci * HW + h * Wd + w] : 0.f;
      }
#pragma unroll
    for (int kk = 0; kk < 9; ++kk) {
      const float* wp = &wgt[(kk * 64 + ci) * 9];
      float a = acc[kk];
#pragma unroll
      for (int q = 0; q < 9; ++q) a = fmaf(v[q], wp[q], a);
      acc[kk] = a;
    }
  }
  const int oBase = f * 9 * 4096 + ho * 64 + wo;
#pragma unroll
  for (int kk = 0; kk < 9; ++kk) out[oBase + kk * 4096] = acc[kk] + bias[kk];
}

// softmax over 72 = T*K*K per (b,ho,wo). scores (16,9,64,64) -> wout (b,pix,72)
__global__ __launch_bounds__(256) void softmax_k(
    const float* __restrict__ sc, float* __restrict__ wout)
{
  const int idx = blockIdx.x * 256 + threadIdx.x;   // 8192 = 2*64*64
  const int b = idx >> 12, pix = idx & 4095;
  float v[72];
  float mx = -1e30f;
#pragma unroll
  for (int t = 0; t < 8; ++t)
#pragma unroll
    for (int kk = 0; kk < 9; ++kk) {
      float s = sc[((b * 8 + t) * 9 + kk) * 4096 + pix];
      v[t * 9 + kk] = s;
      mx = fmaxf(mx, s);
    }
  float sum = 0.f;
#pragma unroll
  for (int i = 0; i < 72; ++i) { v[i] = __expf(v[i] - mx); sum += v[i]; }
  float inv = 1.f / sum;
#pragma unroll
  for (int i = 0; i < 72; ++i) wout[idx * 72 + i] = v[i] * inv;
}

// weighted patch reduce: out[b,c,ho,wo] = sum_{t,i,j} w[b,ho,wo,t,i,j]*x5[...]
__global__ __launch_bounds__(256) void gather_k(
    const float* __restrict__ x5, const float* __restrict__ wts,
    float* __restrict__ out)
{
  const int cgrp = blockIdx.x;   // 8 channel groups of 8
  const int ho = blockIdx.y;     // 64
  const int b = blockIdx.z;      // 2
  __shared__ float wl[64 * 73];  // pad 72->73: no bank conflicts
  const float* wsrc = &wts[(b * 4096 + ho * 64) * 72];
  for (int e = threadIdx.x; e < 64 * 72; e += 256) {
    int wo = e / 72, k = e - wo * 72;
    wl[wo * 73 + k] = wsrc[e];
  }
  __syncthreads();
  const int wo = threadIdx.x & 63;
  const int sub = threadIdx.x >> 6;   // 0..3
  const int hc = 2 * ho - 1, wc = 2 * wo - 1;
#pragma unroll
  for (int cc2 = 0; cc2 < 2; ++cc2) {
    const int c = cgrp * 8 + sub * 2 + cc2;
    float acc = 0.f;
#pragma unroll 1
    for (int t = 0; t < 8; ++t) {
      const int base = ((b * 8 + t) * 64 + c) * HW;
      const float* wrow = &wl[wo * 73 + t * 9];
#pragma unroll
      for (int di = 0; di < 3; ++di) {
        int h = min(max(hc + di, 0), 127);
#pragma unroll
        for (int dj = 0; dj < 3; ++dj) {
          int w = min(max(wc + dj, 0), 127);
          acc = fmaf(x5[base + h * Wd + w], wrow[di * 3 + dj], acc);
        }
      }
    }
    out[((b * 64 + c) * 64 + ho) * 64 + wo] = acc;
  }
}

extern "C" void kernel_launch(void* const* d_in, const int* in_sizes, int n_in,
                              void* d_out, int out_size, void* d_ws, size_t ws_size,
                              hipStream_t stream)
{
  const float* x   = (const float*)d_in[0];
  const float* w1  = (const float*)d_in[1];
  const float* b1  = (const float*)d_in[2];
  const float* w2  = (const float*)d_in[3];
  const float* b2  = (const float*)d_in[4];
  const float* wk1 = (const float*)d_in[5];
  const float* bk1 = (const float*)d_in[6];
  const float* wk2 = (const float*)d_in[7];
  const float* bk2 = (const float*)d_in[8];
  const float* wk3 = (const float*)d_in[9];
  const float* bk3 = (const float*)d_in[10];
  float* outp = (float*)d_out;

  char* ws = (char*)d_ws;
  float* A      = (float*)ws;                      // 64 MB: x5 (frame-major)
  float* Bf     = (float*)(ws + 67108864);         // 64 MB: res1, then k
  float* Cf     = (float*)(ws + 134217728);        // 64 MB: kf2
  float* scores = (float*)(ws + 201326592);        // 2.25 MB
  float* wbuf   = (float*)(ws + 201326592 + 2359296); // 2.25 MB
  (void)ws_size; (void)in_sizes; (void)n_in; (void)out_size;

  dim3 cgrid(4, 16, 16);   // 32w x 8h tiles, 16 frames
  // 1: res1 = lrelu(conv(xf, w1) + b1)                 -> Bf
  conv3x3_k<true,  false, true,  false><<<cgrid, 1024, 0, stream>>>(
      x, w1, b1, nullptr, Bf);
  // 2: x5 = x + conv(shift(res1)*res1, w2) + b2        -> A
  conv3x3_k<false, true,  false, true ><<<cgrid, 1024, 0, stream>>>(
      Bf, w2, b2, x, A);
  // 3: k = wk1 @ x5 + bk1                              -> Bf
  conv1x1_k<<<dim3(64, 16), 256, 0, stream>>>(A, wk1, bk1, Bf);
  // 4: kf2 = lrelu(conv(k, wk2) + bk2)                 -> Cf
  conv3x3_k<false, false, true,  false><<<cgrid, 1024, 0, stream>>>(
      Bf, wk2, bk2, nullptr, Cf);
  // 5: scores = conv_s2(kf2, wk3) + bk3                -> scores
  convs2_k<<<dim3(16, 16), 256, 0, stream>>>(Cf, wk3, bk3, scores);
  // 6: softmax over 72
  softmax_k<<<dim3(32), 256, 0, stream>>>(scores, wbuf);
  // 7: weighted gather reduce
  gather_k<<<dim3(8, 64, 2), 256, 0, stream>>>(A, wbuf, outp);
}

// Round 3
// 1772.509 us; speedup vs baseline: 2.3828x; 1.8234x over previous
//
#include <hip/hip_runtime.h>
#include <hip/hip_bf16.h>
#include <math.h>

#define Wd 128
#define Hd 128
#define HW 16384
#define CH 64
#define TT 8
#define NEGS 0.2f

// 3x3 conv, pad=1, stride=1, 64->64 ch, one frame per blockIdx.z.
// Block: 1024 threads = 256 pixels (32w x 8h) x 4 cout-groups of 16.
// R2 fix: cout-group index forced to SGPR via readfirstlane so weight
// addresses are provably wave-uniform -> s_load (R1: divergent-looking
// cg=tid>>8 made every weight a per-lane global_load_dword; VALUBusy 35%).
template<bool IN_X, bool SHIFTMUL, bool LRELU, bool RESID_X>
__global__ __launch_bounds__(1024) void conv3x3_k(
    const float* __restrict__ in, const float* __restrict__ wgt,
    const float* __restrict__ bias, const float* __restrict__ xres,
    float* __restrict__ out)
{
  const int f = blockIdx.z;
  const int h0 = blockIdx.y * 8;
  const int w0 = blockIdx.x * 32;
  const int tid = threadIdx.x;
  const int p = tid & 255;          // pixel within 32x8 tile
  const int cg = __builtin_amdgcn_readfirstlane(tid >> 8);  // 0..3, SGPR
  const int px = p & 31, py = p >> 5;

  __shared__ float tile[8 * 340];   // 8 cin x 10 rows x 34 cols

  float acc[16];
#pragma unroll
  for (int i = 0; i < 16; ++i) acc[i] = 0.f;

  int inBase, cstr;
  if (IN_X) { int b = f >> 3, t = f & 7; inBase = (b * 512 + t) * HW; cstr = TT * HW; }
  else      { inBase = f * CH * HW; cstr = HW; }

#pragma unroll 1
  for (int cb = 0; cb < 64; cb += 8) {
    __syncthreads();
#pragma unroll 1
    for (int e = tid; e < 8 * 340; e += 1024) {
      int ci = e / 340; int rem = e - ci * 340;
      int r = rem / 34; int cc2 = rem - r * 34;
      int gh = h0 + r - 1, gw = w0 + cc2 - 1;
      const int c = cb + ci;
      float v = 0.f;
      if (gh >= 0 && gh < Hd && gw >= 0 && gw < Wd) {
        v = in[inBase + c * cstr + gh * Wd + gw];
        if (SHIFTMUL) {
          int g = c >> 4;           // 16-channel shift groups
          int ph = gh, pw = gw;
          if (g == 0) pw -= 4; else if (g == 1) pw += 4;
          else if (g == 2) ph -= 4; else ph += 4;
          float pv = 0.f;
          if (ph >= 0 && ph < Hd && pw >= 0 && pw < Wd)
            pv = in[inBase + c * cstr + ph * Wd + pw];
          v *= pv;
        }
      }
      tile[e] = v;
    }
    __syncthreads();

#pragma unroll 1
    for (int ci = 0; ci < 8; ++ci) {
      const float* tp = &tile[ci * 340 + py * 34 + px];
      float v00 = tp[0],  v01 = tp[1],  v02 = tp[2];
      float v10 = tp[34], v11 = tp[35], v12 = tp[36];
      float v20 = tp[68], v21 = tp[69], v22 = tp[70];
      const int cin = cb + ci;
      const float* wb = &wgt[(cg * 16 * 64 + cin) * 9];   // uniform -> s_load
#pragma unroll
      for (int co = 0; co < 16; ++co) {
        const float* wp = wb + co * 576;                  // (co*64)*9
        float a = acc[co];
        a = fmaf(v00, wp[0], a);
        a = fmaf(v01, wp[1], a);
        a = fmaf(v02, wp[2], a);
        a = fmaf(v10, wp[3], a);
        a = fmaf(v11, wp[4], a);
        a = fmaf(v12, wp[5], a);
        a = fmaf(v20, wp[6], a);
        a = fmaf(v21, wp[7], a);
        a = fmaf(v22, wp[8], a);
        acc[co] = a;
      }
    }
  }

  const int oh = h0 + py, ow = w0 + px;
  const int outBase = f * CH * HW + oh * Wd + ow;
  int xBase = 0;
  if (RESID_X) { int b = f >> 3, t = f & 7; xBase = (b * 512 + t) * HW + oh * Wd + ow; }
#pragma unroll
  for (int co = 0; co < 16; ++co) {
    const int c = cg * 16 + co;
    float r = acc[co] + bias[c];
    if (LRELU) r = (r >= 0.f) ? r : NEGS * r;
    if (RESID_X) r += xres[xBase + c * (TT * HW)];
    out[outBase + c * HW] = r;
  }
}

// 1x1 conv (k = wk1 @ x5 + bk1), frame-major in/out. One pixel per thread,
// all 64 inputs held in registers, 4 x (64x16) FMA passes.
__global__ __launch_bounds__(256) void conv1x1_k(
    const float* __restrict__ in, const float* __restrict__ w,
    const float* __restrict__ b, float* __restrict__ out)
{
  const int f = blockIdx.y;
  const int pix = blockIdx.x * 256 + threadIdx.x;
  const int base = f * CH * HW + pix;
  float v[64];
#pragma unroll
  for (int c = 0; c < 64; ++c) v[c] = in[base + c * HW];
#pragma unroll 1
  for (int cg = 0; cg < 4; ++cg) {
    float acc[16];
#pragma unroll
    for (int o = 0; o < 16; ++o) acc[o] = b[cg * 16 + o];
#pragma unroll
    for (int c = 0; c < 64; ++c) {
      const float* wp = &w[cg * 16 * 64 + c];
#pragma unroll
      for (int o = 0; o < 16; ++o)
        acc[o] = fmaf(v[c], wp[o * 64], acc[o]);
    }
#pragma unroll
    for (int o = 0; o < 16; ++o)
      out[base + (cg * 16 + o) * HW] = acc[o];
  }
}

// 3x3 conv, stride 2, pad 1, 64 -> 9 channels (scores). Output (16,9,64,64).
__global__ __launch_bounds__(256) void convs2_k(
    const float* __restrict__ in, const float* __restrict__ wgt,
    const float* __restrict__ bias, float* __restrict__ out)
{
  const int f = blockIdx.y;
  const int idx = blockIdx.x * 256 + threadIdx.x;   // 4096 out pixels
  const int wo = idx & 63, ho = idx >> 6;
  const int inBase = f * CH * HW;
  const int hc = 2 * ho - 1, wc = 2 * wo - 1;
  float acc[9];
#pragma unroll
  for (int i = 0; i < 9; ++i) acc[i] = 0.f;
#pragma unroll 1
  for (int ci = 0; ci < 64; ++ci) {
    float v[9];
#pragma unroll
    for (int di = 0; di < 3; ++di)
#pragma unroll
      for (int dj = 0; dj < 3; ++dj) {
        int h = hc + di, w = wc + dj;
        v[di * 3 + dj] = (h >= 0 && h < Hd && w >= 0 && w < Wd)
            ? in[inBase + ci * HW + h * Wd + w] : 0.f;
      }
#pragma unroll
    for (int kk = 0; kk < 9; ++kk) {
      const float* wp = &wgt[(kk * 64 + ci) * 9];
      float a = acc[kk];
#pragma unroll
      for (int q = 0; q < 9; ++q) a = fmaf(v[q], wp[q], a);
      acc[kk] = a;
    }
  }
  const int oBase = f * 9 * 4096 + ho * 64 + wo;
#pragma unroll
  for (int kk = 0; kk < 9; ++kk) out[oBase + kk * 4096] = acc[kk] + bias[kk];
}

// softmax over 72 = T*K*K per (b,ho,wo). scores (16,9,64,64) -> wout (b,pix,72)
__global__ __launch_bounds__(256) void softmax_k(
    const float* __restrict__ sc, float* __restrict__ wout)
{
  const int idx = blockIdx.x * 256 + threadIdx.x;   // 8192 = 2*64*64
  const int b = idx >> 12, pix = idx & 4095;
  float v[72];
  float mx = -1e30f;
#pragma unroll
  for (int t = 0; t < 8; ++t)
#pragma unroll
    for (int kk = 0; kk < 9; ++kk) {
      float s = sc[((b * 8 + t) * 9 + kk) * 4096 + pix];
      v[t * 9 + kk] = s;
      mx = fmaxf(mx, s);
    }
  float sum = 0.f;
#pragma unroll
  for (int i = 0; i < 72; ++i) { v[i] = __expf(v[i] - mx); sum += v[i]; }
  float inv = 1.f / sum;
#pragma unroll
  for (int i = 0; i < 72; ++i) wout[idx * 72 + i] = v[i] * inv;
}

// weighted patch reduce: out[b,c,ho,wo] = sum_{t,i,j} w[b,ho,wo,t,i,j]*x5[...]
__global__ __launch_bounds__(256) void gather_k(
    const float* __restrict__ x5, const float* __restrict__ wts,
    float* __restrict__ out)
{
  const int cgrp = blockIdx.x;   // 8 channel groups of 8
  const int ho = blockIdx.y;     // 64
  const int b = blockIdx.z;      // 2
  __shared__ float wl[64 * 73];  // pad 72->73: no bank conflicts
  const float* wsrc = &wts[(b * 4096 + ho * 64) * 72];
  for (int e = threadIdx.x; e < 64 * 72; e += 256) {
    int wo = e / 72, k = e - wo * 72;
    wl[wo * 73 + k] = wsrc[e];
  }
  __syncthreads();
  const int wo = threadIdx.x & 63;
  const int sub = threadIdx.x >> 6;   // 0..3
  const int hc = 2 * ho - 1, wc = 2 * wo - 1;
#pragma unroll
  for (int cc2 = 0; cc2 < 2; ++cc2) {
    const int c = cgrp * 8 + sub * 2 + cc2;
    float acc = 0.f;
#pragma unroll 1
    for (int t = 0; t < 8; ++t) {
      const int base = ((b * 8 + t) * 64 + c) * HW;
      const float* wrow = &wl[wo * 73 + t * 9];
#pragma unroll
      for (int di = 0; di < 3; ++di) {
        int h = min(max(hc + di, 0), 127);
#pragma unroll
        for (int dj = 0; dj < 3; ++dj) {
          int w = min(max(wc + dj, 0), 127);
          acc = fmaf(x5[base + h * Wd + w], wrow[di * 3 + dj], acc);
        }
      }
    }
    out[((b * 64 + c) * 64 + ho) * 64 + wo] = acc;
  }
}

extern "C" void kernel_launch(void* const* d_in, const int* in_sizes, int n_in,
                              void* d_out, int out_size, void* d_ws, size_t ws_size,
                              hipStream_t stream)
{
  const float* x   = (const float*)d_in[0];
  const float* w1  = (const float*)d_in[1];
  const float* b1  = (const float*)d_in[2];
  const float* w2  = (const float*)d_in[3];
  const float* b2  = (const float*)d_in[4];
  const float* wk1 = (const float*)d_in[5];
  const float* bk1 = (const float*)d_in[6];
  const float* wk2 = (const float*)d_in[7];
  const float* bk2 = (const float*)d_in[8];
  const float* wk3 = (const float*)d_in[9];
  const float* bk3 = (const float*)d_in[10];
  float* outp = (float*)d_out;

  char* ws = (char*)d_ws;
  float* A      = (float*)ws;                      // 64 MB: x5 (frame-major)
  float* Bf     = (float*)(ws + 67108864);         // 64 MB: res1, then k
  float* Cf     = (float*)(ws + 134217728);        // 64 MB: kf2
  float* scores = (float*)(ws + 201326592);        // 2.25 MB
  float* wbuf   = (float*)(ws + 201326592 + 2359296); // 2.25 MB
  (void)ws_size; (void)in_sizes; (void)n_in; (void)out_size;

  dim3 cgrid(4, 16, 16);   // 32w x 8h tiles, 16 frames
  // 1: res1 = lrelu(conv(xf, w1) + b1)                 -> Bf
  conv3x3_k<true,  false, true,  false><<<cgrid, 1024, 0, stream>>>(
      x, w1, b1, nullptr, Bf);
  // 2: x5 = x + conv(shift(res1)*res1, w2) + b2        -> A
  conv3x3_k<false, true,  false, true ><<<cgrid, 1024, 0, stream>>>(
      Bf, w2, b2, x, A);
  // 3: k = wk1 @ x5 + bk1                              -> Bf
  conv1x1_k<<<dim3(64, 16), 256, 0, stream>>>(A, wk1, bk1, Bf);
  // 4: kf2 = lrelu(conv(k, wk2) + bk2)                 -> Cf
  conv3x3_k<false, false, true,  false><<<cgrid, 1024, 0, stream>>>(
      Bf, wk2, bk2, nullptr, Cf);
  // 5: scores = conv_s2(kf2, wk3) + bk3                -> scores
  convs2_k<<<dim3(16, 16), 256, 0, stream>>>(Cf, wk3, bk3, scores);
  // 6: softmax over 72
  softmax_k<<<dim3(32), 256, 0, stream>>>(scores, wbuf);
  // 7: weighted gather reduce
  gather_k<<<dim3(8, 64, 2), 256, 0, stream>>>(A, wbuf, outp);
}

// Round 4
// 544.451 us; speedup vs baseline: 7.7575x; 3.2556x over previous
//
#include <hip/hip_runtime.h>
#include <hip/hip_bf16.h>
#include <math.h>

#define Wd 128
#define Hd 128
#define HW 16384
#define CH 64
#define TT 8
#define NEGS 0.2f

typedef short bf16x8 __attribute__((ext_vector_type(8)));
typedef float f32x4 __attribute__((ext_vector_type(4)));

__device__ __forceinline__ short tobf(float v) {
  __hip_bfloat16 h = __float2bfloat16(v);
  return __builtin_bit_cast(short, h);
}

// Pack one 3x3 weight set (O=64,I=64,3,3) fp32 -> bf16 [cout][k], k=(dy*3+dx)*64+cin.
__global__ __launch_bounds__(256) void packw_k(const float* __restrict__ w,
                                               short* __restrict__ out)
{
  int i = blockIdx.x * 256 + threadIdx.x;       // 36864
  int cout = i / 576, k = i - cout * 576;
  int off = k >> 6, cin = k & 63;
  int dy = off / 3, dx = off - dy * 3;
  out[i] = tobf(w[((cout * 64 + cin) * 3 + dy) * 3 + dx]);
}

// 3x3 conv 64->64, pad=1, via bf16 MFMA implicit GEMM.
// Block = 256 thr (4 waves), out tile 32w x 8h, each wave 64cout x 64pix (2 rows).
// LDS: X[340 pix][64 cin] bf16, XOR-swizzled (cin_oct ^= pix&7) for conflict-free b128.
// Weights: pre-packed bf16 [cout][576] read from global (L1/L2-resident, 72KB).
template<bool IN_X, bool SHIFTMUL, bool LRELU, bool RESID_X>
__global__ __launch_bounds__(256) void conv3x3_mfma_k(
    const float* __restrict__ in, const short* __restrict__ wb,
    const float* __restrict__ bias, const float* __restrict__ xres,
    float* __restrict__ out)
{
  const int f = blockIdx.z;
  const int h0 = blockIdx.y * 8;
  const int w0 = blockIdx.x * 32;
  const int tid = threadIdx.x;
  const int lane = tid & 63;
  const int wv = tid >> 6;        // wave 0..3 -> out rows 2wv..2wv+1
  const int l15 = lane & 15;
  const int oct = lane >> 4;      // 0..3

  __shared__ __align__(16) short Xs[340 * 64];   // 43.5 KB

  int inBase, cstr;
  if (IN_X) { int b = f >> 3, t = f & 7; inBase = (b * 512 + t) * HW; cstr = TT * HW; }
  else      { inBase = f * CH * HW; cstr = HW; }

  // ---- stage fp32 -> bf16 swizzled LDS: thread owns tile pixels tid, tid+256 ----
  const int p0 = tid, p1 = tid + 256;
  const int r0 = p0 / 34, c0 = p0 - r0 * 34;
  const int r1 = p1 / 34, c1 = p1 - r1 * 34;
  const int gh0 = h0 + r0 - 1, gw0 = w0 + c0 - 1;
  const int gh1 = h0 + r1 - 1, gw1 = w0 + c1 - 1;
  const bool ok0 = (gh0 >= 0 && gh0 < Hd && gw0 >= 0 && gw0 < Wd);
  const bool ok1 = (p1 < 340) && (gh1 >= 0 && gh1 < Hd && gw1 >= 0 && gw1 < Wd);
  const int sw0 = (p0 & 7) << 3;  // swizzle XOR (in elems)
  const int sw1 = (p1 & 7) << 3;

#pragma unroll 1
  for (int cin = 0; cin < 64; ++cin) {
    const int cOff = inBase + cin * cstr;
    const int swo = (cin >> 3) << 3;   // oct*8
    const int low = cin & 7;
    float v = 0.f;
    if (ok0) {
      v = in[cOff + gh0 * Wd + gw0];
      if (SHIFTMUL) {
        int g = cin >> 4;
        int ph = gh0, pw = gw0;
        if (g == 0) pw -= 4; else if (g == 1) pw += 4;
        else if (g == 2) ph -= 4; else ph += 4;
        float pv = 0.f;
        if (ph >= 0 && ph < Hd && pw >= 0 && pw < Wd) pv = in[cOff + ph * Wd + pw];
        v *= pv;
      }
    }
    Xs[p0 * 64 + (swo ^ sw0) + low] = tobf(v);
    if (p1 < 340) {
      float v1 = 0.f;
      if (ok1) {
        v1 = in[cOff + gh1 * Wd + gw1];
        if (SHIFTMUL) {
          int g = cin >> 4;
          int ph = gh1, pw = gw1;
          if (g == 0) pw -= 4; else if (g == 1) pw += 4;
          else if (g == 2) ph -= 4; else ph += 4;
          float pv = 0.f;
          if (ph >= 0 && ph < Hd && pw >= 0 && pw < Wd) pv = in[cOff + ph * Wd + pw];
          v1 *= pv;
        }
      }
      Xs[p1 * 64 + (swo ^ sw1) + low] = tobf(v1);
    }
  }
  __syncthreads();

  // ---- MFMA main: 18 k-steps of 32; wave computes 64cout x 64pix ----
  f32x4 acc[4][4];   // [cg][pt]
#pragma unroll
  for (int i = 0; i < 4; ++i)
#pragma unroll
    for (int j = 0; j < 4; ++j) acc[i][j] = (f32x4)0.f;

#pragma unroll 1
  for (int s = 0; s < 18; ++s) {
    const int o = s >> 1;          // spatial offset 0..8
    const int dy = o / 3, dx = o - dy * 3;
    const int half = s & 1;        // cin half (0:0-31, 1:32-63)
    bf16x8 a[4];
#pragma unroll
    for (int cg = 0; cg < 4; ++cg)
      a[cg] = *(const bf16x8*)(wb + (cg * 16 + l15) * 576 + s * 32 + oct * 8);
#pragma unroll
    for (int pt = 0; pt < 4; ++pt) {
      const int r = 2 * wv + (pt >> 1) + dy;
      const int c = (pt & 1) * 16 + dx + l15;
      const int p = r * 34 + c;
      const int co = ((half * 4 + oct) ^ (p & 7)) << 3;
      bf16x8 b = *(const bf16x8*)(Xs + p * 64 + co);
#pragma unroll
      for (int cg = 0; cg < 4; ++cg)
        acc[cg][pt] = __builtin_amdgcn_mfma_f32_16x16x32_bf16(a[cg], b, acc[cg][pt], 0, 0, 0);
    }
  }

  // ---- epilogue: bias (+lrelu) (+residual), fp32 store ----
  int xresBase = 0;
  if (RESID_X) { int b = f >> 3, t = f & 7; xresBase = (b * 512 + t) * HW; }
  const int outF = f * CH * HW;
#pragma unroll
  for (int cg = 0; cg < 4; ++cg)
#pragma unroll
    for (int pt = 0; pt < 4; ++pt) {
      const int py = h0 + 2 * wv + (pt >> 1);
      const int px = w0 + (pt & 1) * 16 + l15;
      const int opix = py * Wd + px;
#pragma unroll
      for (int rr = 0; rr < 4; ++rr) {
        const int cout = cg * 16 + oct * 4 + rr;
        float v = acc[cg][pt][rr] + bias[cout];
        if (LRELU) v = (v >= 0.f) ? v : NEGS * v;
        if (RESID_X) v += xres[xresBase + cout * (TT * HW) + opix];
        out[outF + cout * HW + opix] = v;
      }
    }
}

// 1x1 conv (k = wk1 @ x5 + bk1), frame-major in/out, fp32.
__global__ __launch_bounds__(256) void conv1x1_k(
    const float* __restrict__ in, const float* __restrict__ w,
    const float* __restrict__ b, float* __restrict__ out)
{
  const int f = blockIdx.y;
  const int pix = blockIdx.x * 256 + threadIdx.x;
  const int base = f * CH * HW + pix;
  float v[64];
#pragma unroll
  for (int c = 0; c < 64; ++c) v[c] = in[base + c * HW];
#pragma unroll 1
  for (int cg = 0; cg < 4; ++cg) {
    float acc[16];
#pragma unroll
    for (int o = 0; o < 16; ++o) acc[o] = b[cg * 16 + o];
#pragma unroll
    for (int c = 0; c < 64; ++c) {
      const float* wp = &w[cg * 16 * 64 + c];
#pragma unroll
      for (int o = 0; o < 16; ++o)
        acc[o] = fmaf(v[c], wp[o * 64], acc[o]);
    }
#pragma unroll
    for (int o = 0; o < 16; ++o)
      out[base + (cg * 16 + o) * HW] = acc[o];
  }
}

// 3x3 conv, stride 2, pad 1, 64 -> 9 channels (scores). Output (16,9,64,64).
__global__ __launch_bounds__(256) void convs2_k(
    const float* __restrict__ in, const float* __restrict__ wgt,
    const float* __restrict__ bias, float* __restrict__ out)
{
  const int f = blockIdx.y;
  const int idx = blockIdx.x * 256 + threadIdx.x;   // 4096 out pixels
  const int wo = idx & 63, ho = idx >> 6;
  const int inBase = f * CH * HW;
  const int hc = 2 * ho - 1, wc = 2 * wo - 1;
  float acc[9];
#pragma unroll
  for (int i = 0; i < 9; ++i) acc[i] = 0.f;
#pragma unroll 1
  for (int ci = 0; ci < 64; ++ci) {
    float v[9];
#pragma unroll
    for (int di = 0; di < 3; ++di)
#pragma unroll
      for (int dj = 0; dj < 3; ++dj) {
        int h = hc + di, w = wc + dj;
        v[di * 3 + dj] = (h >= 0 && h < Hd && w >= 0 && w < Wd)
            ? in[inBase + ci * HW + h * Wd + w] : 0.f;
      }
#pragma unroll
    for (int kk = 0; kk < 9; ++kk) {
      const float* wp = &wgt[(kk * 64 + ci) * 9];
      float a = acc[kk];
#pragma unroll
      for (int q = 0; q < 9; ++q) a = fmaf(v[q], wp[q], a);
      acc[kk] = a;
    }
  }
  const int oBase = f * 9 * 4096 + ho * 64 + wo;
#pragma unroll
  for (int kk = 0; kk < 9; ++kk) out[oBase + kk * 4096] = acc[kk] + bias[kk];
}

// softmax over 72 = T*K*K per (b,ho,wo). scores (16,9,64,64) -> wout (b,pix,72)
__global__ __launch_bounds__(256) void softmax_k(
    const float* __restrict__ sc, float* __restrict__ wout)
{
  const int idx = blockIdx.x * 256 + threadIdx.x;   // 8192 = 2*64*64
  const int b = idx >> 12, pix = idx & 4095;
  float v[72];
  float mx = -1e30f;
#pragma unroll
  for (int t = 0; t < 8; ++t)
#pragma unroll
    for (int kk = 0; kk < 9; ++kk) {
      float s = sc[((b * 8 + t) * 9 + kk) * 4096 + pix];
      v[t * 9 + kk] = s;
      mx = fmaxf(mx, s);
    }
  float sum = 0.f;
#pragma unroll
  for (int i = 0; i < 72; ++i) { v[i] = __expf(v[i] - mx); sum += v[i]; }
  float inv = 1.f / sum;
#pragma unroll
  for (int i = 0; i < 72; ++i) wout[idx * 72 + i] = v[i] * inv;
}

// weighted patch reduce: out[b,c,ho,wo] = sum_{t,i,j} w[b,ho,wo,t,i,j]*x5[...]
__global__ __launch_bounds__(256) void gather_k(
    const float* __restrict__ x5, const float* __restrict__ wts,
    float* __restrict__ out)
{
  const int cgrp = blockIdx.x;   // 8 channel groups of 8
  const int ho = blockIdx.y;     // 64
  const int b = blockIdx.z;      // 2
  __shared__ float wl[64 * 73];  // pad 72->73: no bank conflicts
  const float* wsrc = &wts[(b * 4096 + ho * 64) * 72];
  for (int e = threadIdx.x; e < 64 * 72; e += 256) {
    int wo = e / 72, k = e - wo * 72;
    wl[wo * 73 + k] = wsrc[e];
  }
  __syncthreads();
  const int wo = threadIdx.x & 63;
  const int sub = threadIdx.x >> 6;   // 0..3
  const int hc = 2 * ho - 1, wc = 2 * wo - 1;
#pragma unroll
  for (int cc2 = 0; cc2 < 2; ++cc2) {
    const int c = cgrp * 8 + sub * 2 + cc2;
    float acc = 0.f;
#pragma unroll 1
    for (int t = 0; t < 8; ++t) {
      const int base = ((b * 8 + t) * 64 + c) * HW;
      const float* wrow = &wl[wo * 73 + t * 9];
#pragma unroll
      for (int di = 0; di < 3; ++di) {
        int h = min(max(hc + di, 0), 127);
#pragma unroll
        for (int dj = 0; dj < 3; ++dj) {
          int w = min(max(wc + dj, 0), 127);
          acc = fmaf(x5[base + h * Wd + w], wrow[di * 3 + dj], acc);
        }
      }
    }
    out[((b * 64 + c) * 64 + ho) * 64 + wo] = acc;
  }
}

extern "C" void kernel_launch(void* const* d_in, const int* in_sizes, int n_in,
                              void* d_out, int out_size, void* d_ws, size_t ws_size,
                              hipStream_t stream)
{
  const float* x   = (const float*)d_in[0];
  const float* w1  = (const float*)d_in[1];
  const float* b1  = (const float*)d_in[2];
  const float* w2  = (const float*)d_in[3];
  const float* b2  = (const float*)d_in[4];
  const float* wk1 = (const float*)d_in[5];
  const float* bk1 = (const float*)d_in[6];
  const float* wk2 = (const float*)d_in[7];
  const float* bk2 = (const float*)d_in[8];
  const float* wk3 = (const float*)d_in[9];
  const float* bk3 = (const float*)d_in[10];
  float* outp = (float*)d_out;

  char* ws = (char*)d_ws;
  float* A      = (float*)ws;                         // 64 MB: x5 (frame-major)
  float* Bf     = (float*)(ws + 67108864);            // 64 MB: res1, then k
  float* Cf     = (float*)(ws + 134217728);           // 64 MB: kf2
  float* scores = (float*)(ws + 201326592);           // 2.25 MB
  float* wbuf   = (float*)(ws + 201326592 + 2359296); // 2.25 MB
  short* Wp1    = (short*)(ws + 206045184);           // 72 KB each, packed bf16
  short* Wp2    = Wp1 + 36864;
  short* Wp4    = Wp2 + 36864;
  (void)ws_size; (void)in_sizes; (void)n_in; (void)out_size;

  // pack weights fp32 -> bf16 [cout][k]
  packw_k<<<dim3(144), 256, 0, stream>>>(w1, Wp1);
  packw_k<<<dim3(144), 256, 0, stream>>>(w2, Wp2);
  packw_k<<<dim3(144), 256, 0, stream>>>(wk2, Wp4);

  dim3 cgrid(4, 16, 16);   // 32w x 8h tiles, 16 frames
  // 1: res1 = lrelu(conv(xf, w1) + b1)                 -> Bf
  conv3x3_mfma_k<true,  false, true,  false><<<cgrid, 256, 0, stream>>>(
      x, Wp1, b1, nullptr, Bf);
  // 2: x5 = x + conv(shift(res1)*res1, w2) + b2        -> A
  conv3x3_mfma_k<false, true,  false, true ><<<cgrid, 256, 0, stream>>>(
      Bf, Wp2, b2, x, A);
  // 3: k = wk1 @ x5 + bk1                              -> Bf
  conv1x1_k<<<dim3(64, 16), 256, 0, stream>>>(A, wk1, bk1, Bf);
  // 4: kf2 = lrelu(conv(k, wk2) + bk2)                 -> Cf
  conv3x3_mfma_k<false, false, true,  false><<<cgrid, 256, 0, stream>>>(
      Bf, Wp4, bk2, nullptr, Cf);
  // 5: scores = conv_s2(kf2, wk3) + bk3                -> scores
  convs2_k<<<dim3(16, 16), 256, 0, stream>>>(Cf, wk3, bk3, scores);
  // 6: softmax over 72
  softmax_k<<<dim3(32), 256, 0, stream>>>(scores, wbuf);
  // 7: weighted gather reduce
  gather_k<<<dim3(8, 64, 2), 256, 0, stream>>>(A, wbuf, outp);
}

// Round 5
// 403.651 us; speedup vs baseline: 10.4634x; 1.3488x over previous
//
#include <hip/hip_runtime.h>
#include <hip/hip_bf16.h>
#include <math.h>

#define Wd 128
#define Hd 128
#define HW 16384
#define CH 64
#define TT 8
#define NEGS 0.2f
#define PW 130                    // padded width/height
#define ROWB (PW * CH * 2)        // padded row bytes = 16640
#define FRB ((size_t)PW * PW * CH)  // padded frame elems (u16)

typedef unsigned short u16;
typedef u16 u16x8 __attribute__((ext_vector_type(8)));
typedef u16 u16x4 __attribute__((ext_vector_type(4)));
typedef short bf16x8 __attribute__((ext_vector_type(8)));
typedef float f32x4 __attribute__((ext_vector_type(4)));

__device__ __forceinline__ u16 tobf(float v) {
  __hip_bfloat16 h = __float2bfloat16(v);
  return __builtin_bit_cast(u16, h);
}
__device__ __forceinline__ float bf2f(u16 u) {
  unsigned x = ((unsigned)u) << 16;
  return __builtin_bit_cast(float, x);
}
__device__ __forceinline__ void gload_lds16(const void* g, void* l) {
  __builtin_amdgcn_global_load_lds(
      (const __attribute__((address_space(1))) unsigned int*)g,
      (__attribute__((address_space(3))) unsigned int*)l, 16, 0, 0);
}

// Pack 3x3 weights (O=64,I=64,3,3) fp32 -> bf16 [cout][k], k=(dy*3+dx)*64+cin.
__global__ __launch_bounds__(256) void packw_k(const float* __restrict__ w,
                                               short* __restrict__ out)
{
  int i = blockIdx.x * 256 + threadIdx.x;       // 36864
  int cout = i / 576, k = i - cout * 576;
  int off = k >> 6, cin = k & 63;
  int dy = off / 3, dx = off - dy * 3;
  out[i] = (short)tobf(w[((cout * 64 + cin) * 3 + dy) * 3 + dx]);
}

// x (B,C,T,H,W) fp32 -> padded swizzled bf16 [f][130][130][64].
// Swizzle: channel-octet unit = (c>>3) ^ (ppw&7); pads = 0.
__global__ __launch_bounds__(256) void xprep_k(const float* __restrict__ x,
                                               u16* __restrict__ outb)
{
  const int f = blockIdx.x, b = f >> 3, t = f & 7;
  const int ph = blockIdx.y;                    // 0..129
  const int u = threadIdx.x & 7;
  const int p0 = threadIdx.x >> 3;              // 0..31
#pragma unroll
  for (int i = 0; i < 5; ++i) {
    const int ppw = p0 + 32 * i;
    if (ppw < PW) {
      const int cb = (u ^ (ppw & 7)) << 3;
      const int h = ph - 1, w = ppw - 1;
      u16x8 pk = (u16x8)0;
      if (h >= 0 && h < Hd && w >= 0 && w < Wd) {
        const float* src = x + (((size_t)(b * 64 + cb) * 8 + t) * HW) + h * Wd + w;
#pragma unroll
        for (int j = 0; j < 8; ++j) pk[j] = tobf(src[(size_t)j * 8 * HW]);
      }
      *(u16x8*)(outb + ((size_t)f * PW + ph) * PW * CH + (size_t)ppw * CH + u * 8) = pk;
    }
  }
}

// sm = r1 * shift(r1), both padded swizzled bf16. 4 groups of 16 ch, shift 4.
__global__ __launch_bounds__(256) void shmul_k(const u16* __restrict__ r1,
                                               u16* __restrict__ sm)
{
  const int f = blockIdx.x;
  const int ph = blockIdx.y;
  const int u = threadIdx.x & 7;
  const int p0 = threadIdx.x >> 3;
#pragma unroll
  for (int i = 0; i < 5; ++i) {
    const int ppw = p0 + 32 * i;
    if (ppw < PW) {
      const int cb = (u ^ (ppw & 7)) << 3;
      const int g = cb >> 4;
      const size_t idx = ((size_t)f * PW + ph) * PW * CH + (size_t)ppw * CH;
      u16x8 v = *(const u16x8*)(r1 + idx + u * 8);
      const int h = ph - 1, w = ppw - 1;
      int dh = 0, dw = 0;
      if (g == 0) dw = -4; else if (g == 1) dw = 4;
      else if (g == 2) dh = -4; else dh = 4;
      const int h2 = h + dh, w2 = w + dw;
      u16x8 pv = (u16x8)0;
      if (h >= 0 && h < Hd && w >= 0 && w < Wd &&
          h2 >= 0 && h2 < Hd && w2 >= 0 && w2 < Wd) {
        const int pph2 = h2 + 1, ppw2 = w2 + 1;
        const int u2 = (cb >> 3) ^ (ppw2 & 7);
        pv = *(const u16x8*)(r1 + ((size_t)f * PW + pph2) * PW * CH +
                             (size_t)ppw2 * CH + u2 * 8);
      }
      u16x8 o;
#pragma unroll
      for (int j = 0; j < 8; ++j) o[j] = tobf(bf2f(v[j]) * bf2f(pv[j]));
      *(u16x8*)(sm + idx + u * 8) = o;
    }
  }
}

// 3x3 conv 64->64 pad=1 via bf16 MFMA. Input: padded swizzled bf16.
// Staging: async global_load_lds (16B), linear LDS = pre-swizzled global rows.
// OUTF32: fp32 [f][c][HW] out (+optional x residual). else: padded bf16 out.
template<bool OUTF32, bool LRELU, bool RESID_X>
__global__ __launch_bounds__(256) void conv3x3_mfma2_k(
    const u16* __restrict__ inp, const short* __restrict__ wb,
    const float* __restrict__ bias, const float* __restrict__ xres,
    float* __restrict__ outf, u16* __restrict__ outb)
{
  const int f = blockIdx.z;
  const int h0 = blockIdx.y * 8;    // padded tile row base == out row base
  const int w0 = blockIdx.x * 32;   // multiple of 8 -> ppw&7 == (tile col)&7
  const int tid = threadIdx.x;
  const int lane = tid & 63;
  const int wv = __builtin_amdgcn_readfirstlane(tid >> 6);
  const int l15 = lane & 15;
  const int oct = lane >> 4;

  __shared__ __align__(16) u16 Xs[340 * 64];   // 43520 B; rows of 4352 B

  // ---- async staging: 43 x 1KB chunks, wave-strided ----
  const char* tbase = (const char*)(inp + ((size_t)f * PW * PW + (size_t)h0 * PW + w0) * CH);
  char* lbase = (char*)&Xs[0];
#pragma unroll 1
  for (int i = wv; i < 43; i += 4) {
    const int ob = i * 1024 + lane * 16;
    if (ob < 43520) {
      const int row = ob / 4352;
      const int rem = ob - row * 4352;
      gload_lds16(tbase + (size_t)row * ROWB + rem, lbase + i * 1024);
    }
  }
  __syncthreads();

  // ---- MFMA: 18 k-steps of 32; wave computes 64cout x 64pix (rows 2wv,2wv+1) ----
  f32x4 acc[4][4];
#pragma unroll
  for (int i = 0; i < 4; ++i)
#pragma unroll
    for (int j = 0; j < 4; ++j) acc[i][j] = (f32x4)0.f;

#pragma unroll 1
  for (int s = 0; s < 18; ++s) {
    const int o = s >> 1;
    const int dy = o / 3, dx = o - dy * 3;
    const int half = s & 1;
    bf16x8 a[4];
#pragma unroll
    for (int cg = 0; cg < 4; ++cg)
      a[cg] = *(const bf16x8*)(wb + (cg * 16 + l15) * 576 + s * 32 + oct * 8);
#pragma unroll
    for (int pt = 0; pt < 4; ++pt) {
      const int r = 2 * wv + (pt >> 1) + dy;
      const int cc = (pt & 1) * 16 + dx + l15;       // tile col 0..33
      const int p = r * 34 + cc;
      const int co = ((half * 4 + oct) ^ (cc & 7)) << 3;
      bf16x8 b = *(const bf16x8*)((const short*)Xs + p * 64 + co);
#pragma unroll
      for (int cg = 0; cg < 4; ++cg)
        acc[cg][pt] = __builtin_amdgcn_mfma_f32_16x16x32_bf16(a[cg], b, acc[cg][pt], 0, 0, 0);
    }
  }

  // ---- epilogue ----
  int xresBase = 0;
  if (RESID_X) { int b = f >> 3, t = f & 7; xresBase = (b * 512 + t) * HW; }
#pragma unroll
  for (int cg = 0; cg < 4; ++cg)
#pragma unroll
    for (int pt = 0; pt < 4; ++pt) {
      const int py = h0 + 2 * wv + (pt >> 1);
      const int px = w0 + (pt & 1) * 16 + l15;
      const int opix = py * Wd + px;
      float v[4];
#pragma unroll
      for (int rr = 0; rr < 4; ++rr) {
        const int cout = cg * 16 + oct * 4 + rr;
        float t2 = acc[cg][pt][rr] + bias[cout];
        if (LRELU) t2 = (t2 >= 0.f) ? t2 : NEGS * t2;
        if (RESID_X) t2 += xres[xresBase + cout * (TT * HW) + opix];
        v[rr] = t2;
      }
      if (OUTF32) {
        const int outF = f * CH * HW;
#pragma unroll
        for (int rr = 0; rr < 4; ++rr)
          outf[outF + (cg * 16 + oct * 4 + rr) * HW + opix] = v[rr];
      } else {
        const int pph = py + 1, ppw = px + 1;
        const int unit = (cg * 2 + (oct >> 1)) ^ (ppw & 7);
        u16x4 pk;
#pragma unroll
        for (int rr = 0; rr < 4; ++rr) pk[rr] = tobf(v[rr]);
        *(u16x4*)(outb + ((size_t)f * PW + pph) * PW * CH + (size_t)ppw * CH +
                  unit * 8 + (oct & 1) * 4) = pk;
      }
    }
}

// 1x1 conv: x5 fp32 [f][c][HW] -> padded swizzled bf16 k.
__global__ __launch_bounds__(256) void conv1x1_k(
    const float* __restrict__ in, const float* __restrict__ w,
    const float* __restrict__ b, u16* __restrict__ outb)
{
  const int f = blockIdx.y;
  const int pix = blockIdx.x * 256 + threadIdx.x;
  const int base = f * CH * HW + pix;
  float v[64];
#pragma unroll
  for (int c = 0; c < 64; ++c) v[c] = in[base + c * HW];
  const int h = pix >> 7, ww = pix & 127;
  const int pph = h + 1, ppw = ww + 1;
  const size_t obase = ((size_t)f * PW + pph) * PW * CH + (size_t)ppw * CH;
#pragma unroll 1
  for (int cg = 0; cg < 4; ++cg) {
    float acc[16];
#pragma unroll
    for (int o = 0; o < 16; ++o) acc[o] = b[cg * 16 + o];
#pragma unroll
    for (int c = 0; c < 64; ++c) {
      const float* wp = &w[cg * 16 * 64 + c];
#pragma unroll
      for (int o = 0; o < 16; ++o)
        acc[o] = fmaf(v[c], wp[o * 64], acc[o]);
    }
#pragma unroll
    for (int half = 0; half < 2; ++half) {
      const int ub = cg * 2 + half;
      const int unit = ub ^ (ppw & 7);
      u16x8 pk;
#pragma unroll
      for (int j = 0; j < 8; ++j) pk[j] = tobf(acc[half * 8 + j]);
      *(u16x8*)(outb + obase + unit * 8) = pk;
    }
  }
}

// stride-2 3x3 conv 64->9 from padded swizzled bf16. Output (16,9,64,64).
__global__ __launch_bounds__(256) void convs2b_k(
    const u16* __restrict__ inb, const float* __restrict__ wgt,
    const float* __restrict__ bias, float* __restrict__ out)
{
  const int f = blockIdx.y;
  const int idx = blockIdx.x * 256 + threadIdx.x;   // 4096
  const int wo = idx & 63, ho = idx >> 6;
  float acc[9];
#pragma unroll
  for (int i = 0; i < 9; ++i) acc[i] = 0.f;
#pragma unroll 1
  for (int di = 0; di < 3; ++di)
#pragma unroll 1
    for (int dj = 0; dj < 3; ++dj) {
      const int pph = 2 * ho + di, ppw = 2 * wo + dj;
      const u16* row = inb + ((size_t)f * PW + pph) * PW * CH + (size_t)ppw * CH;
      const int q = di * 3 + dj;
#pragma unroll
      for (int ub = 0; ub < 8; ++ub) {
        const int unit = ub ^ (ppw & 7);
        u16x8 pk = *(const u16x8*)(row + unit * 8);
#pragma unroll
        for (int j = 0; j < 8; ++j) {
          const float xv = bf2f(pk[j]);
          const int c = ub * 8 + j;
#pragma unroll
          for (int kk = 0; kk < 9; ++kk)
            acc[kk] = fmaf(xv, wgt[(kk * 64 + c) * 9 + q], acc[kk]);
        }
      }
    }
  const int oBase = f * 9 * 4096 + ho * 64 + wo;
#pragma unroll
  for (int kk = 0; kk < 9; ++kk) out[oBase + kk * 4096] = acc[kk] + bias[kk];
}

// softmax over 72 per (b,ho,wo). scores (16,9,64,64) -> wout (b,pix,72)
__global__ __launch_bounds__(256) void softmax_k(
    const float* __restrict__ sc, float* __restrict__ wout)
{
  const int idx = blockIdx.x * 256 + threadIdx.x;
  const int b = idx >> 12, pix = idx & 4095;
  float v[72];
  float mx = -1e30f;
#pragma unroll
  for (int t = 0; t < 8; ++t)
#pragma unroll
    for (int kk = 0; kk < 9; ++kk) {
      float s = sc[((b * 8 + t) * 9 + kk) * 4096 + pix];
      v[t * 9 + kk] = s;
      mx = fmaxf(mx, s);
    }
  float sum = 0.f;
#pragma unroll
  for (int i = 0; i < 72; ++i) { v[i] = __expf(v[i] - mx); sum += v[i]; }
  float inv = 1.f / sum;
#pragma unroll
  for (int i = 0; i < 72; ++i) wout[idx * 72 + i] = v[i] * inv;
}

// weighted patch reduce from x5 fp32 [f][c][HW].
__global__ __launch_bounds__(256) void gather_k(
    const float* __restrict__ x5, const float* __restrict__ wts,
    float* __restrict__ out)
{
  const int cgrp = blockIdx.x;
  const int ho = blockIdx.y;
  const int b = blockIdx.z;
  __shared__ float wl[64 * 73];
  const float* wsrc = &wts[(b * 4096 + ho * 64) * 72];
  for (int e = threadIdx.x; e < 64 * 72; e += 256) {
    int wo = e / 72, k = e - wo * 72;
    wl[wo * 73 + k] = wsrc[e];
  }
  __syncthreads();
  const int wo = threadIdx.x & 63;
  const int sub = threadIdx.x >> 6;
  const int hc = 2 * ho - 1, wc = 2 * wo - 1;
#pragma unroll
  for (int cc2 = 0; cc2 < 2; ++cc2) {
    const int c = cgrp * 8 + sub * 2 + cc2;
    float acc = 0.f;
#pragma unroll 1
    for (int t = 0; t < 8; ++t) {
      const int base = ((b * 8 + t) * 64 + c) * HW;
      const float* wrow = &wl[wo * 73 + t * 9];
#pragma unroll
      for (int di = 0; di < 3; ++di) {
        int h = min(max(hc + di, 0), 127);
#pragma unroll
        for (int dj = 0; dj < 3; ++dj) {
          int w = min(max(wc + dj, 0), 127);
          acc = fmaf(x5[base + h * Wd + w], wrow[di * 3 + dj], acc);
        }
      }
    }
    out[((b * 64 + c) * 64 + ho) * 64 + wo] = acc;
  }
}

extern "C" void kernel_launch(void* const* d_in, const int* in_sizes, int n_in,
                              void* d_out, int out_size, void* d_ws, size_t ws_size,
                              hipStream_t stream)
{
  const float* x   = (const float*)d_in[0];
  const float* w1  = (const float*)d_in[1];
  const float* b1  = (const float*)d_in[2];
  const float* w2  = (const float*)d_in[3];
  const float* b2  = (const float*)d_in[4];
  const float* wk1 = (const float*)d_in[5];
  const float* bk1 = (const float*)d_in[6];
  const float* wk2 = (const float*)d_in[7];
  const float* bk2 = (const float*)d_in[8];
  const float* wk3 = (const float*)d_in[9];
  const float* bk3 = (const float*)d_in[10];
  float* outp = (float*)d_out;

  const size_t PADB = (size_t)16 * PW * PW * CH * 2;   // 34,611,200 B
  char* ws = (char*)d_ws;
  float* x5     = (float*)ws;                          // 64 MB fp32 [f][c][HW]
  u16*  P1      = (u16*)(ws + 67108864);               // xbfp then kbfp
  u16*  P2      = (u16*)(ws + 67108864 + PADB);        // res1bfp then kf2bfp
  u16*  P3      = (u16*)(ws + 67108864 + 2 * PADB);    // smbfp
  float* scores = (float*)(ws + 67108864 + 3 * PADB);  // 2.25 MB
  float* wbuf   = (float*)(ws + 67108864 + 3 * PADB + 2359296);
  short* Wp1    = (short*)(ws + 67108864 + 3 * PADB + 2 * 2359296);
  short* Wp2    = Wp1 + 36864;
  short* Wp4    = Wp2 + 36864;
  (void)ws_size; (void)in_sizes; (void)n_in; (void)out_size;

  packw_k<<<dim3(144), 256, 0, stream>>>(w1, Wp1);
  packw_k<<<dim3(144), 256, 0, stream>>>(w2, Wp2);
  packw_k<<<dim3(144), 256, 0, stream>>>(wk2, Wp4);

  // zero pads of res1bfp (interior written by conv1; pads must stay 0)
  hipMemsetAsync(P2, 0, PADB, stream);
  // x -> padded swizzled bf16
  xprep_k<<<dim3(16, PW), 256, 0, stream>>>(x, P1);

  dim3 cgrid(4, 16, 16);
  // 1: res1 = lrelu(conv(x, w1) + b1)        -> P2 (bf16 padded)
  conv3x3_mfma2_k<false, true, false><<<cgrid, 256, 0, stream>>>(
      P1, Wp1, b1, nullptr, nullptr, P2);
  // 2: sm = res1 * shift(res1)               -> P3
  shmul_k<<<dim3(16, PW), 256, 0, stream>>>(P2, P3);
  // 3: x5 = x + conv(sm, w2) + b2            -> x5 (fp32)
  conv3x3_mfma2_k<true, false, true><<<cgrid, 256, 0, stream>>>(
      P3, Wp2, b2, x, x5, nullptr);
  // 4: k = wk1 @ x5 + bk1                    -> P1 (bf16 padded; memset pads)
  hipMemsetAsync(P1, 0, PADB, stream);
  conv1x1_k<<<dim3(64, 16), 256, 0, stream>>>(x5, wk1, bk1, P1);
  // 5: kf2 = lrelu(conv(k, wk2) + bk2)       -> P2 (pads still 0)
  conv3x3_mfma2_k<false, true, false><<<cgrid, 256, 0, stream>>>(
      P1, Wp4, bk2, nullptr, nullptr, P2);
  // 6: scores = conv_s2(kf2, wk3) + bk3
  convs2b_k<<<dim3(16, 16), 256, 0, stream>>>(P2, wk3, bk3, scores);
  // 7: softmax over 72
  softmax_k<<<dim3(32), 256, 0, stream>>>(scores, wbuf);
  // 8: weighted gather
  gather_k<<<dim3(8, 64, 2), 256, 0, stream>>>(x5, wbuf, outp);
}

// Round 6
// 306.256 us; speedup vs baseline: 13.7910x; 1.3180x over previous
//
#include <hip/hip_runtime.h>
#include <hip/hip_bf16.h>
#include <math.h>

#define Wd 128
#define Hd 128
#define HW 16384
#define CH 64
#define TT 8
#define NEGS 0.2f
#define PW 130                    // padded width/height
#define ROWB (PW * CH * 2)        // padded row bytes = 16640

typedef unsigned short u16;
typedef u16 u16x8 __attribute__((ext_vector_type(8)));
typedef u16 u16x4 __attribute__((ext_vector_type(4)));
typedef short bf16x8 __attribute__((ext_vector_type(8)));
typedef float f32x4 __attribute__((ext_vector_type(4)));

__device__ __forceinline__ u16 tobf(float v) {
  __hip_bfloat16 h = __float2bfloat16(v);
  return __builtin_bit_cast(u16, h);
}
__device__ __forceinline__ float bf2f(u16 u) {
  unsigned x = ((unsigned)u) << 16;
  return __builtin_bit_cast(float, x);
}
__device__ __forceinline__ void gload_lds16(const void* g, void* l) {
  __builtin_amdgcn_global_load_lds(
      (const __attribute__((address_space(1))) unsigned int*)g,
      (__attribute__((address_space(3))) unsigned int*)l, 16, 0, 0);
}

// Pack 3x3 weights (O=64,I=64,3,3) fp32 -> bf16 [cout][k], k=(dy*3+dx)*64+cin.
__global__ __launch_bounds__(256) void packw_k(const float* __restrict__ w,
                                               short* __restrict__ out)
{
  int i = blockIdx.x * 256 + threadIdx.x;       // 36864
  int cout = i / 576, k = i - cout * 576;
  int off = k >> 6, cin = k & 63;
  int dy = off / 3, dx = off - dy * 3;
  out[i] = (short)tobf(w[((cout * 64 + cin) * 3 + dy) * 3 + dx]);
}

// Pack 1x1 weights (64,64) fp32 -> bf16 row-major [kout][cin].
__global__ __launch_bounds__(256) void packw1_k(const float* __restrict__ w,
                                                short* __restrict__ out)
{
  int i = blockIdx.x * 256 + threadIdx.x;       // 4096
  out[i] = (short)tobf(w[i]);
}

// x (B,C,T,H,W) fp32 -> padded swizzled bf16 [f][130][130][64].
// Swizzle: channel-octet unit = (c>>3) ^ (ppw&7); pads = 0.
__global__ __launch_bounds__(256) void xprep_k(const float* __restrict__ x,
                                               u16* __restrict__ outb)
{
  const int f = blockIdx.x, b = f >> 3, t = f & 7;
  const int ph = blockIdx.y;                    // 0..129
  const int u = threadIdx.x & 7;
  const int p0 = threadIdx.x >> 3;              // 0..31
#pragma unroll
  for (int i = 0; i < 5; ++i) {
    const int ppw = p0 + 32 * i;
    if (ppw < PW) {
      const int cb = (u ^ (ppw & 7)) << 3;
      const int h = ph - 1, w = ppw - 1;
      u16x8 pk = (u16x8)0;
      if (h >= 0 && h < Hd && w >= 0 && w < Wd) {
        const float* src = x + (((size_t)(b * 64 + cb) * 8 + t) * HW) + h * Wd + w;
#pragma unroll
        for (int j = 0; j < 8; ++j) pk[j] = tobf(src[(size_t)j * 8 * HW]);
      }
      *(u16x8*)(outb + ((size_t)f * PW + ph) * PW * CH + (size_t)ppw * CH + u * 8) = pk;
    }
  }
}

// sm = r1 * shift(r1), both padded swizzled bf16. 4 groups of 16 ch, shift 4.
__global__ __launch_bounds__(256) void shmul_k(const u16* __restrict__ r1,
                                               u16* __restrict__ sm)
{
  const int f = blockIdx.x;
  const int ph = blockIdx.y;
  const int u = threadIdx.x & 7;
  const int p0 = threadIdx.x >> 3;
#pragma unroll
  for (int i = 0; i < 5; ++i) {
    const int ppw = p0 + 32 * i;
    if (ppw < PW) {
      const int cb = (u ^ (ppw & 7)) << 3;
      const int g = cb >> 4;
      const size_t idx = ((size_t)f * PW + ph) * PW * CH + (size_t)ppw * CH;
      u16x8 v = *(const u16x8*)(r1 + idx + u * 8);
      const int h = ph - 1, w = ppw - 1;
      int dh = 0, dw = 0;
      if (g == 0) dw = -4; else if (g == 1) dw = 4;
      else if (g == 2) dh = -4; else dh = 4;
      const int h2 = h + dh, w2 = w + dw;
      u16x8 pv = (u16x8)0;
      if (h >= 0 && h < Hd && w >= 0 && w < Wd &&
          h2 >= 0 && h2 < Hd && w2 >= 0 && w2 < Wd) {
        const int pph2 = h2 + 1, ppw2 = w2 + 1;
        const int u2 = (cb >> 3) ^ (ppw2 & 7);
        pv = *(const u16x8*)(r1 + ((size_t)f * PW + pph2) * PW * CH +
                             (size_t)ppw2 * CH + u2 * 8);
      }
      u16x8 o;
#pragma unroll
      for (int j = 0; j < 8; ++j) o[j] = tobf(bf2f(v[j]) * bf2f(pv[j]));
      *(u16x8*)(sm + idx + u * 8) = o;
    }
  }
}

// 3x3 conv 64->64 pad=1 via bf16 MFMA. Input: padded swizzled bf16.
// Staging: async global_load_lds (16B), linear LDS = pre-swizzled global rows.
// Output: padded swizzled bf16 (+lrelu).
__global__ __launch_bounds__(256) void conv3x3_mfma2_k(
    const u16* __restrict__ inp, const short* __restrict__ wb,
    const float* __restrict__ bias, u16* __restrict__ outb)
{
  const int f = blockIdx.z;
  const int h0 = blockIdx.y * 8;
  const int w0 = blockIdx.x * 32;
  const int tid = threadIdx.x;
  const int lane = tid & 63;
  const int wv = __builtin_amdgcn_readfirstlane(tid >> 6);
  const int l15 = lane & 15;
  const int oct = lane >> 4;

  __shared__ __align__(16) u16 Xs[340 * 64];   // 43520 B; rows of 4352 B

  const char* tbase = (const char*)(inp + ((size_t)f * PW * PW + (size_t)h0 * PW + w0) * CH);
  char* lbase = (char*)&Xs[0];
#pragma unroll 1
  for (int i = wv; i < 43; i += 4) {
    const int ob = i * 1024 + lane * 16;
    if (ob < 43520) {
      const int row = ob / 4352;
      const int rem = ob - row * 4352;
      gload_lds16(tbase + (size_t)row * ROWB + rem, lbase + i * 1024);
    }
  }
  __syncthreads();

  f32x4 acc[4][4];
#pragma unroll
  for (int i = 0; i < 4; ++i)
#pragma unroll
    for (int j = 0; j < 4; ++j) acc[i][j] = (f32x4)0.f;

#pragma unroll 1
  for (int s = 0; s < 18; ++s) {
    const int o = s >> 1;
    const int dy = o / 3, dx = o - dy * 3;
    const int half = s & 1;
    bf16x8 a[4];
#pragma unroll
    for (int cg = 0; cg < 4; ++cg)
      a[cg] = *(const bf16x8*)(wb + (cg * 16 + l15) * 576 + s * 32 + oct * 8);
#pragma unroll
    for (int pt = 0; pt < 4; ++pt) {
      const int r = 2 * wv + (pt >> 1) + dy;
      const int cc = (pt & 1) * 16 + dx + l15;
      const int p = r * 34 + cc;
      const int co = ((half * 4 + oct) ^ (cc & 7)) << 3;
      bf16x8 b = *(const bf16x8*)((const short*)Xs + p * 64 + co);
#pragma unroll
      for (int cg = 0; cg < 4; ++cg)
        acc[cg][pt] = __builtin_amdgcn_mfma_f32_16x16x32_bf16(a[cg], b, acc[cg][pt], 0, 0, 0);
    }
  }

#pragma unroll
  for (int cg = 0; cg < 4; ++cg)
#pragma unroll
    for (int pt = 0; pt < 4; ++pt) {
      const int py = h0 + 2 * wv + (pt >> 1);
      const int px = w0 + (pt & 1) * 16 + l15;
      const int pph = py + 1, ppw = px + 1;
      const int unit = (cg * 2 + (oct >> 1)) ^ (ppw & 7);
      u16x4 pk;
#pragma unroll
      for (int rr = 0; rr < 4; ++rr) {
        const int cout = cg * 16 + oct * 4 + rr;
        float t2 = acc[cg][pt][rr] + bias[cout];
        t2 = (t2 >= 0.f) ? t2 : NEGS * t2;
        pk[rr] = tobf(t2);
      }
      *(u16x4*)(outb + ((size_t)f * PW + pph) * PW * CH + (size_t)ppw * CH +
                unit * 8 + (oct & 1) * 4) = pk;
    }
}

// Fused: x5 = x + conv3x3(sm, w2) + b2  (fp32 out for gather)
//        k  = wk1 @ x5 + bk1           (bf16 padded swizzled out)
// The wave's acc holds all 64 channels of x5 for its 64 pixels -> 1x1 conv
// is 2 more MFMA k-steps via an LDS round-trip (reusing Xs as Ys[256][64]).
__global__ __launch_bounds__(256) void conv3x3_x5_k(
    const u16* __restrict__ inp, const short* __restrict__ wb,
    const float* __restrict__ bias, const float* __restrict__ xres,
    const short* __restrict__ w1b, const float* __restrict__ b1x1,
    float* __restrict__ outf, u16* __restrict__ outb)
{
  const int f = blockIdx.z;
  const int h0 = blockIdx.y * 8;
  const int w0 = blockIdx.x * 32;
  const int tid = threadIdx.x;
  const int lane = tid & 63;
  const int wv = __builtin_amdgcn_readfirstlane(tid >> 6);
  const int l15 = lane & 15;
  const int oct = lane >> 4;

  __shared__ __align__(16) u16 Xs[340 * 64];

  const char* tbase = (const char*)(inp + ((size_t)f * PW * PW + (size_t)h0 * PW + w0) * CH);
  char* lbase = (char*)&Xs[0];
#pragma unroll 1
  for (int i = wv; i < 43; i += 4) {
    const int ob = i * 1024 + lane * 16;
    if (ob < 43520) {
      const int row = ob / 4352;
      const int rem = ob - row * 4352;
      gload_lds16(tbase + (size_t)row * ROWB + rem, lbase + i * 1024);
    }
  }
  __syncthreads();

  f32x4 acc[4][4];
#pragma unroll
  for (int i = 0; i < 4; ++i)
#pragma unroll
    for (int j = 0; j < 4; ++j) acc[i][j] = (f32x4)0.f;

#pragma unroll 1
  for (int s = 0; s < 18; ++s) {
    const int o = s >> 1;
    const int dy = o / 3, dx = o - dy * 3;
    const int half = s & 1;
    bf16x8 a[4];
#pragma unroll
    for (int cg = 0; cg < 4; ++cg)
      a[cg] = *(const bf16x8*)(wb + (cg * 16 + l15) * 576 + s * 32 + oct * 8);
#pragma unroll
    for (int pt = 0; pt < 4; ++pt) {
      const int r = 2 * wv + (pt >> 1) + dy;
      const int cc = (pt & 1) * 16 + dx + l15;
      const int p = r * 34 + cc;
      const int co = ((half * 4 + oct) ^ (cc & 7)) << 3;
      bf16x8 b = *(const bf16x8*)((const short*)Xs + p * 64 + co);
#pragma unroll
      for (int cg = 0; cg < 4; ++cg)
        acc[cg][pt] = __builtin_amdgcn_mfma_f32_16x16x32_bf16(a[cg], b, acc[cg][pt], 0, 0, 0);
    }
  }

  __syncthreads();             // all Xs reads done -> safe to reuse as Ys
  u16* Ys = &Xs[0];            // [256 pix][64 ch], same XOR swizzle on (p2&7)

  // ---- epilogue 1: x5 = acc + b2 + x ; store fp32 + stash bf16 in LDS ----
  const int b0 = f >> 3, t0 = f & 7;
  const int xresBase = (b0 * 512 + t0) * HW;
  const int outF = f * CH * HW;
#pragma unroll
  for (int cg = 0; cg < 4; ++cg)
#pragma unroll
    for (int pt = 0; pt < 4; ++pt) {
      const int lr = 2 * wv + (pt >> 1);
      const int lc = (pt & 1) * 16 + l15;
      const int p2 = lr * 32 + lc;
      const int opix = (h0 + lr) * Wd + (w0 + lc);
      u16x4 pk;
#pragma unroll
      for (int rr = 0; rr < 4; ++rr) {
        const int cout = cg * 16 + oct * 4 + rr;
        float v = acc[cg][pt][rr] + bias[cout] + xres[xresBase + cout * (TT * HW) + opix];
        outf[outF + cout * HW + opix] = v;
        pk[rr] = tobf(v);
      }
      const int unit = (cg * 2 + (oct >> 1)) ^ (p2 & 7);
      *(u16x4*)(Ys + p2 * 64 + unit * 8 + (oct & 1) * 4) = pk;
    }
  __syncthreads();

  // ---- phase 2: k = wk1 @ x5 + bk1 (2 MFMA k-steps) ----
  f32x4 acc2[4][4];
#pragma unroll
  for (int i = 0; i < 4; ++i)
#pragma unroll
    for (int j = 0; j < 4; ++j) acc2[i][j] = (f32x4)0.f;

#pragma unroll
  for (int s = 0; s < 2; ++s) {
    bf16x8 a2[4];
#pragma unroll
    for (int cg = 0; cg < 4; ++cg)
      a2[cg] = *(const bf16x8*)(w1b + (cg * 16 + l15) * 64 + s * 32 + oct * 8);
#pragma unroll
    for (int pt = 0; pt < 4; ++pt) {
      const int p2 = (2 * wv + (pt >> 1)) * 32 + (pt & 1) * 16 + l15;
      const int co = ((s * 4 + oct) ^ (p2 & 7)) << 3;
      bf16x8 b = *(const bf16x8*)((const short*)Ys + p2 * 64 + co);
#pragma unroll
      for (int cg = 0; cg < 4; ++cg)
        acc2[cg][pt] = __builtin_amdgcn_mfma_f32_16x16x32_bf16(a2[cg], b, acc2[cg][pt], 0, 0, 0);
    }
  }

  // ---- epilogue 2: k + bk1 -> bf16 padded swizzled ----
#pragma unroll
  for (int cg = 0; cg < 4; ++cg)
#pragma unroll
    for (int pt = 0; pt < 4; ++pt) {
      const int py = h0 + 2 * wv + (pt >> 1);
      const int px = w0 + (pt & 1) * 16 + l15;
      const int pph = py + 1, ppw = px + 1;
      const int unit = (cg * 2 + (oct >> 1)) ^ (ppw & 7);
      u16x4 pk;
#pragma unroll
      for (int rr = 0; rr < 4; ++rr) {
        const int kout = cg * 16 + oct * 4 + rr;
        pk[rr] = tobf(acc2[cg][pt][rr] + b1x1[kout]);
      }
      *(u16x4*)(outb + ((size_t)f * PW + pph) * PW * CH + (size_t)ppw * CH +
                unit * 8 + (oct & 1) * 4) = pk;
    }
}

// stride-2 3x3 conv 64->9 from padded swizzled bf16. Output (16,9,64,64).
__global__ __launch_bounds__(256) void convs2b_k(
    const u16* __restrict__ inb, const float* __restrict__ wgt,
    const float* __restrict__ bias, float* __restrict__ out)
{
  const int f = blockIdx.y;
  const int idx = blockIdx.x * 256 + threadIdx.x;   // 4096
  const int wo = idx & 63, ho = idx >> 6;
  float acc[9];
#pragma unroll
  for (int i = 0; i < 9; ++i) acc[i] = 0.f;
#pragma unroll 1
  for (int di = 0; di < 3; ++di)
#pragma unroll 1
    for (int dj = 0; dj < 3; ++dj) {
      const int pph = 2 * ho + di, ppw = 2 * wo + dj;
      const u16* row = inb + ((size_t)f * PW + pph) * PW * CH + (size_t)ppw * CH;
      const int q = di * 3 + dj;
#pragma unroll
      for (int ub = 0; ub < 8; ++ub) {
        const int unit = ub ^ (ppw & 7);
        u16x8 pk = *(const u16x8*)(row + unit * 8);
#pragma unroll
        for (int j = 0; j < 8; ++j) {
          const float xv = bf2f(pk[j]);
          const int c = ub * 8 + j;
#pragma unroll
          for (int kk = 0; kk < 9; ++kk)
            acc[kk] = fmaf(xv, wgt[(kk * 64 + c) * 9 + q], acc[kk]);
        }
      }
    }
  const int oBase = f * 9 * 4096 + ho * 64 + wo;
#pragma unroll
  for (int kk = 0; kk < 9; ++kk) out[oBase + kk * 4096] = acc[kk] + bias[kk];
}

// softmax over 72 per (b,ho,wo). scores (16,9,64,64) -> wout (b,pix,72)
__global__ __launch_bounds__(256) void softmax_k(
    const float* __restrict__ sc, float* __restrict__ wout)
{
  const int idx = blockIdx.x * 256 + threadIdx.x;
  const int b = idx >> 12, pix = idx & 4095;
  float v[72];
  float mx = -1e30f;
#pragma unroll
  for (int t = 0; t < 8; ++t)
#pragma unroll
    for (int kk = 0; kk < 9; ++kk) {
      float s = sc[((b * 8 + t) * 9 + kk) * 4096 + pix];
      v[t * 9 + kk] = s;
      mx = fmaxf(mx, s);
    }
  float sum = 0.f;
#pragma unroll
  for (int i = 0; i < 72; ++i) { v[i] = __expf(v[i] - mx); sum += v[i]; }
  float inv = 1.f / sum;
#pragma unroll
  for (int i = 0; i < 72; ++i) wout[idx * 72 + i] = v[i] * inv;
}

// weighted patch reduce from x5 fp32 [f][c][HW].
__global__ __launch_bounds__(256) void gather_k(
    const float* __restrict__ x5, const float* __restrict__ wts,
    float* __restrict__ out)
{
  const int cgrp = blockIdx.x;
  const int ho = blockIdx.y;
  const int b = blockIdx.z;
  __shared__ float wl[64 * 73];
  const float* wsrc = &wts[(b * 4096 + ho * 64) * 72];
  for (int e = threadIdx.x; e < 64 * 72; e += 256) {
    int wo = e / 72, k = e - wo * 72;
    wl[wo * 73 + k] = wsrc[e];
  }
  __syncthreads();
  const int wo = threadIdx.x & 63;
  const int sub = threadIdx.x >> 6;
  const int hc = 2 * ho - 1, wc = 2 * wo - 1;
#pragma unroll
  for (int cc2 = 0; cc2 < 2; ++cc2) {
    const int c = cgrp * 8 + sub * 2 + cc2;
    float acc = 0.f;
#pragma unroll 1
    for (int t = 0; t < 8; ++t) {
      const int base = ((b * 8 + t) * 64 + c) * HW;
      const float* wrow = &wl[wo * 73 + t * 9];
#pragma unroll
      for (int di = 0; di < 3; ++di) {
        int h = min(max(hc + di, 0), 127);
#pragma unroll
        for (int dj = 0; dj < 3; ++dj) {
          int w = min(max(wc + dj, 0), 127);
          acc = fmaf(x5[base + h * Wd + w], wrow[di * 3 + dj], acc);
        }
      }
    }
    out[((b * 64 + c) * 64 + ho) * 64 + wo] = acc;
  }
}

extern "C" void kernel_launch(void* const* d_in, const int* in_sizes, int n_in,
                              void* d_out, int out_size, void* d_ws, size_t ws_size,
                              hipStream_t stream)
{
  const float* x   = (const float*)d_in[0];
  const float* w1  = (const float*)d_in[1];
  const float* b1  = (const float*)d_in[2];
  const float* w2  = (const float*)d_in[3];
  const float* b2  = (const float*)d_in[4];
  const float* wk1 = (const float*)d_in[5];
  const float* bk1 = (const float*)d_in[6];
  const float* wk2 = (const float*)d_in[7];
  const float* bk2 = (const float*)d_in[8];
  const float* wk3 = (const float*)d_in[9];
  const float* bk3 = (const float*)d_in[10];
  float* outp = (float*)d_out;

  const size_t PADB = (size_t)16 * PW * PW * CH * 2;   // 34,611,200 B
  char* ws = (char*)d_ws;
  float* x5     = (float*)ws;                          // 64 MB fp32 [f][c][HW]
  u16*  P1      = (u16*)(ws + 67108864);               // xbfp, then k
  u16*  P2      = (u16*)(ws + 67108864 + PADB);        // res1, then kf2
  u16*  P3      = (u16*)(ws + 67108864 + 2 * PADB);    // sm
  float* scores = (float*)(ws + 67108864 + 3 * PADB);  // 2.25 MB
  float* wbuf   = (float*)(ws + 67108864 + 3 * PADB + 2359296);
  short* Wp1    = (short*)(ws + 67108864 + 3 * PADB + 2 * 2359296);
  short* Wp2    = Wp1 + 36864;
  short* Wp4    = Wp2 + 36864;
  short* Wk1b   = Wp4 + 36864;                         // 4096 bf16
  (void)ws_size; (void)in_sizes; (void)n_in; (void)out_size;

  packw_k<<<dim3(144), 256, 0, stream>>>(w1, Wp1);
  packw_k<<<dim3(144), 256, 0, stream>>>(w2, Wp2);
  packw_k<<<dim3(144), 256, 0, stream>>>(wk2, Wp4);
  packw1_k<<<dim3(16), 256, 0, stream>>>(wk1, Wk1b);

  // zero pads of res1 (interior written by conv1; pads must stay 0)
  hipMemsetAsync(P2, 0, PADB, stream);
  // x -> padded swizzled bf16
  xprep_k<<<dim3(16, PW), 256, 0, stream>>>(x, P1);

  dim3 cgrid(4, 16, 16);
  // 1: res1 = lrelu(conv(x, w1) + b1)            -> P2
  conv3x3_mfma2_k<<<cgrid, 256, 0, stream>>>(P1, Wp1, b1, P2);
  // 2: sm = res1 * shift(res1)                   -> P3
  shmul_k<<<dim3(16, PW), 256, 0, stream>>>(P2, P3);
  // P1's last reader (conv1) is done; zero its pads for the k-write
  hipMemsetAsync(P1, 0, PADB, stream);
  // 3: x5 = x + conv(sm, w2) + b2 (fp32) ; k = wk1@x5 + bk1 (bf16) -> x5, P1
  conv3x3_x5_k<<<cgrid, 256, 0, stream>>>(P3, Wp2, b2, x, Wk1b, bk1, x5, P1);
  // 4: kf2 = lrelu(conv(k, wk2) + bk2)           -> P2 (pads still 0)
  conv3x3_mfma2_k<<<cgrid, 256, 0, stream>>>(P1, Wp4, bk2, P2);
  // 5: scores = conv_s2(kf2, wk3) + bk3
  convs2b_k<<<dim3(16, 16), 256, 0, stream>>>(P2, wk3, bk3, scores);
  // 6: softmax over 72
  softmax_k<<<dim3(32), 256, 0, stream>>>(scores, wbuf);
  // 7: weighted gather
  gather_k<<<dim3(8, 64, 2), 256, 0, stream>>>(x5, wbuf, outp);
}

// Round 7
// 262.261 us; speedup vs baseline: 16.1045x; 1.1678x over previous
//
#include <hip/hip_runtime.h>
#include <hip/hip_bf16.h>
#include <math.h>

#define Wd 128
#define Hd 128
#define HW 16384
#define CH 64
#define TT 8
#define NEGS 0.2f
#define PW 130                    // padded width/height
#define ROWB (PW * CH * 2)        // padded row bytes = 16640

typedef unsigned short u16;
typedef u16 u16x8 __attribute__((ext_vector_type(8)));
typedef u16 u16x4 __attribute__((ext_vector_type(4)));
typedef short bf16x8 __attribute__((ext_vector_type(8)));
typedef float f32x4 __attribute__((ext_vector_type(4)));

__device__ __forceinline__ u16 tobf(float v) {
  __hip_bfloat16 h = __float2bfloat16(v);
  return __builtin_bit_cast(u16, h);
}
__device__ __forceinline__ float bf2f(u16 u) {
  unsigned x = ((unsigned)u) << 16;
  return __builtin_bit_cast(float, x);
}
__device__ __forceinline__ void gload_lds16(const void* g, void* l) {
  __builtin_amdgcn_global_load_lds(
      (const __attribute__((address_space(1))) unsigned int*)g,
      (__attribute__((address_space(3))) unsigned int*)l, 16, 0, 0);
}

// Pack 3x3 weights (O=64,I=64,3,3) fp32 -> bf16 [cout][k] with GRANULE XOR
// swizzle (granule gi = cout*72 + k/8, stored at gi ^ (cout&7)) so LDS
// A-fragment reads (16 lanes = 16 couts, stride 72 granules) are conflict-free.
__global__ __launch_bounds__(256) void packw_k(const float* __restrict__ w,
                                               short* __restrict__ out)
{
  int i = blockIdx.x * 256 + threadIdx.x;       // 36864
  int cout = i / 576, k = i - cout * 576;
  int off = k >> 6, cin = k & 63;
  int dy = off / 3, dx = off - dy * 3;
  int gi = cout * 72 + (k >> 3);
  int go = ((gi ^ (cout & 7)) << 3) + (k & 7);
  out[go] = (short)tobf(w[((cout * 64 + cin) * 3 + dy) * 3 + dx]);
}

// Pack 1x1 weights (64,64) fp32 -> bf16 row-major [kout][cin] (linear).
__global__ __launch_bounds__(256) void packw1_k(const float* __restrict__ w,
                                                short* __restrict__ out)
{
  int i = blockIdx.x * 256 + threadIdx.x;       // 4096
  out[i] = (short)tobf(w[i]);
}

// x (B,C,T,H,W) fp32 -> padded swizzled bf16 [f][130][130][64].
// Swizzle: channel-octet unit = (c>>3) ^ (ppw&7); pads = 0.
__global__ __launch_bounds__(256) void xprep_k(const float* __restrict__ x,
                                               u16* __restrict__ outb)
{
  const int f = blockIdx.x, b = f >> 3, t = f & 7;
  const int ph = blockIdx.y;                    // 0..129
  const int u = threadIdx.x & 7;
  const int p0 = threadIdx.x >> 3;              // 0..31
#pragma unroll
  for (int i = 0; i < 5; ++i) {
    const int ppw = p0 + 32 * i;
    if (ppw < PW) {
      const int cb = (u ^ (ppw & 7)) << 3;
      const int h = ph - 1, w = ppw - 1;
      u16x8 pk = (u16x8)0;
      if (h >= 0 && h < Hd && w >= 0 && w < Wd) {
        const float* src = x + (((size_t)(b * 64 + cb) * 8 + t) * HW) + h * Wd + w;
#pragma unroll
        for (int j = 0; j < 8; ++j) pk[j] = tobf(src[(size_t)j * 8 * HW]);
      }
      *(u16x8*)(outb + ((size_t)f * PW + ph) * PW * CH + (size_t)ppw * CH + u * 8) = pk;
    }
  }
}

// Zero the 1-pixel pad ring of a padded bf16 buffer (all 16 frames).
// 4128 granules of 16B per frame.
__global__ __launch_bounds__(256) void padzero_k(u16* __restrict__ buf)
{
  const int f = blockIdx.y;
  u16* fb = buf + (size_t)f * PW * PW * CH;
  const int g = blockIdx.x * 256 + threadIdx.x;
  if (g >= 4128) return;
  size_t off;
  if (g < 1040)      off = (size_t)g * 8;                              // row 0
  else if (g < 2080) off = (size_t)129 * PW * CH + (size_t)(g - 1040) * 8;  // row 129
  else if (g < 3104) { int r = (g - 2080) >> 3, u = (g - 2080) & 7;
                       off = ((size_t)(r + 1) * PW + 0) * CH + u * 8; }     // col 0
  else               { int r = (g - 3104) >> 3, u = (g - 3104) & 7;
                       off = ((size_t)(r + 1) * PW + 129) * CH + u * 8; }   // col 129
  *(u16x8*)(fb + off) = (u16x8)0;
}

// Persistent double-buffered 3x3 conv 64->64 (pad=1) via bf16 MFMA + lrelu.
// Grid = 256 blocks (f*16 + hy), each block owns an 8-row stripe and walks
// 4 tiles of 32 cols. LDS: weights 73728B (staged once) + 2 x 44032B tile
// buffers. Compute phase has ZERO global VMEM (A from LDS, bias preloaded),
// so the next tile's global_load_lds stays in flight through the MFMAs and
// drains only at the handoff barrier (T3 2-phase pattern).
__global__ __launch_bounds__(256) void conv3x3_pers_k(
    const u16* __restrict__ inp, const short* __restrict__ wsw,
    const float* __restrict__ bias, u16* __restrict__ outb)
{
  extern __shared__ __align__(16) char smem[];
  short* Ws = (short*)smem;                          // 73728 B
  u16* Xb0 = (u16*)(smem + 73728);                   // 44032 B
  u16* Xb1 = (u16*)(smem + 73728 + 44032);           // 44032 B

  const int bid = blockIdx.x;
  const int f = bid >> 4, hy = bid & 15;
  const int h0 = hy * 8;
  const int tid = threadIdx.x;
  const int lane = tid & 63;
  const int wv = __builtin_amdgcn_readfirstlane(tid >> 6);
  const int l15 = lane & 15;
  const int oct = lane >> 4;

  f32x4 b4[4];
#pragma unroll
  for (int cg = 0; cg < 4; ++cg)
#pragma unroll
    for (int rr = 0; rr < 4; ++rr)
      b4[cg][rr] = bias[cg * 16 + oct * 4 + rr];

  // stage weights once (72 x 1KB chunks)
  {
    const char* gs = (const char*)wsw;
    char* ld = (char*)Ws;
#pragma unroll 1
    for (int i = wv; i < 72; i += 4)
      gload_lds16(gs + i * 1024 + lane * 16, ld + i * 1024);
  }

  const char* fbp = (const char*)(inp + (size_t)f * PW * PW * CH);

  // stage tile 0 (43 x 1KB chunks; 512B tail garbage lands in unread LDS)
  {
    const char* tb = fbp + (size_t)h0 * ROWB;
    char* ld = (char*)Xb0;
#pragma unroll 1
    for (int i = wv; i < 43; i += 4) {
      const int ob = i * 1024 + lane * 16;
      const int row = ob / 4352;
      const int rem = ob - row * 4352;
      gload_lds16(tb + (size_t)row * ROWB + rem, ld + i * 1024);
    }
  }

#pragma unroll 1
  for (int it = 0; it < 4; ++it) {
    __syncthreads();                               // drains stage(it) (+weights at it=0)
    u16* Xc = (it & 1) ? Xb1 : Xb0;
    u16* Xn = (it & 1) ? Xb0 : Xb1;
    if (it < 3) {                                  // prefetch next tile, stays in flight
      const char* tb = fbp + (size_t)h0 * ROWB + (size_t)(it + 1) * 32 * CH * 2;
      char* ld = (char*)Xn;
#pragma unroll 1
      for (int i = wv; i < 43; i += 4) {
        const int ob = i * 1024 + lane * 16;
        const int row = ob / 4352;
        const int rem = ob - row * 4352;
        gload_lds16(tb + (size_t)row * ROWB + rem, ld + i * 1024);
      }
    }
    const int w0 = it * 32;

    f32x4 acc[4][4];
#pragma unroll
    for (int i = 0; i < 4; ++i)
#pragma unroll
      for (int j = 0; j < 4; ++j) acc[i][j] = (f32x4)0.f;

#pragma unroll 1
    for (int s = 0; s < 18; ++s) {
      const int o = s >> 1;
      const int dy = o / 3, dx = o - dy * 3;
      const int half = s & 1;
      bf16x8 a[4];
#pragma unroll
      for (int cg = 0; cg < 4; ++cg) {
        const int gi = (cg * 16 + l15) * 72 + s * 4 + oct;
        a[cg] = *(const bf16x8*)(Ws + ((gi ^ (l15 & 7)) << 3));
      }
#pragma unroll
      for (int pt = 0; pt < 4; ++pt) {
        const int r = 2 * wv + (pt >> 1) + dy;
        const int cc = (pt & 1) * 16 + dx + l15;
        const int p = r * 34 + cc;
        const int co = ((half * 4 + oct) ^ (cc & 7)) << 3;
        bf16x8 b = *(const bf16x8*)((const short*)Xc + p * 64 + co);
#pragma unroll
        for (int cg = 0; cg < 4; ++cg)
          acc[cg][pt] = __builtin_amdgcn_mfma_f32_16x16x32_bf16(a[cg], b, acc[cg][pt], 0, 0, 0);
      }
    }

    // epilogue: bias + lrelu -> bf16 padded swizzled (stores drain at next barrier)
#pragma unroll
    for (int cg = 0; cg < 4; ++cg)
#pragma unroll
      for (int pt = 0; pt < 4; ++pt) {
        const int py = h0 + 2 * wv + (pt >> 1);
        const int px = w0 + (pt & 1) * 16 + l15;
        const int pph = py + 1, ppw = px + 1;
        const int unit = (cg * 2 + (oct >> 1)) ^ (ppw & 7);
        u16x4 pk;
#pragma unroll
        for (int rr = 0; rr < 4; ++rr) {
          float t2 = acc[cg][pt][rr] + b4[cg][rr];
          t2 = (t2 >= 0.f) ? t2 : NEGS * t2;
          pk[rr] = tobf(t2);
        }
        *(u16x4*)(outb + ((size_t)f * PW + pph) * PW * CH + (size_t)ppw * CH +
                  unit * 8 + (oct & 1) * 4) = pk;
      }
  }
}

// Fused: sm = res1*shift(res1) computed during staging (kills shmul kernel);
//        x5 = x + conv3x3(sm, w2) + b2  (fp32 [f][c][HW] out for gather)
//        k  = wk1 @ x5 + bk1            (bf16 padded swizzled out)
__global__ __launch_bounds__(256) void conv3x3_x5_k(
    const u16* __restrict__ inp, const short* __restrict__ wb,
    const float* __restrict__ bias, const float* __restrict__ xres,
    const short* __restrict__ w1b, const float* __restrict__ b1x1,
    float* __restrict__ outf, u16* __restrict__ outb)
{
  const int f = blockIdx.z;
  const int h0 = blockIdx.y * 8;
  const int w0 = blockIdx.x * 32;
  const int tid = threadIdx.x;
  const int lane = tid & 63;
  const int wv = __builtin_amdgcn_readfirstlane(tid >> 6);
  const int l15 = lane & 15;
  const int oct = lane >> 4;

  __shared__ __align__(16) u16 Xs[340 * 64];

  // ---- fused shift-mul staging: sm tile -> LDS (v*pv lane-wise) ----
  const size_t fbase = (size_t)f * PW * PW * CH;
#pragma unroll 1
  for (int e = tid; e < 2720; e += 256) {
    const int us = e & 7;
    const int pix = e >> 3;
    const int r = pix / 34;
    const int cc = pix - r * 34;
    const int ph = h0 + r;
    const int ppw = w0 + cc;
    const int ub = us ^ (cc & 7);          // physical channel octet
    const int g = ub >> 1;                  // 16-ch shift group
    const int dw = (g == 0) ? -4 : (g == 1) ? 4 : 0;
    const int dh = (g == 2) ? -4 : (g == 3) ? 4 : 0;
    u16x8 v = *(const u16x8*)(inp + fbase + ((size_t)ph * PW + ppw) * CH + us * 8);
    const int h2 = ph + dh, w2 = ppw + dw;  // padded coords of shift source
    const bool okp = (h2 >= 1 && h2 <= Hd && w2 >= 1 && w2 <= Wd);
    const int h2c = min(max(h2, 0), PW - 1);
    const int w2c = min(max(w2, 0), PW - 1);
    const int u2 = (dw != 0) ? (us ^ 4) : us;   // (ppw±4)&7 == (ppw&7)^4
    u16x8 pv = *(const u16x8*)(inp + fbase + ((size_t)h2c * PW + w2c) * CH + u2 * 8);
    u16x8 o;
#pragma unroll
    for (int j = 0; j < 8; ++j) {
      float pr = okp ? bf2f(v[j]) * bf2f(pv[j]) : 0.f;
      o[j] = tobf(pr);
    }
    *(u16x8*)((u16*)Xs + pix * 64 + us * 8) = o;
  }
  __syncthreads();

  f32x4 acc[4][4];
#pragma unroll
  for (int i = 0; i < 4; ++i)
#pragma unroll
    for (int j = 0; j < 4; ++j) acc[i][j] = (f32x4)0.f;

#pragma unroll 1
  for (int s = 0; s < 18; ++s) {
    const int o = s >> 1;
    const int dy = o / 3, dx = o - dy * 3;
    const int half = s & 1;
    bf16x8 a[4];
#pragma unroll
    for (int cg = 0; cg < 4; ++cg) {
      const int gi = (cg * 16 + l15) * 72 + s * 4 + oct;   // swizzled pack
      a[cg] = *(const bf16x8*)(wb + ((gi ^ (l15 & 7)) << 3));
    }
#pragma unroll
    for (int pt = 0; pt < 4; ++pt) {
      const int r = 2 * wv + (pt >> 1) + dy;
      const int cc = (pt & 1) * 16 + dx + l15;
      const int p = r * 34 + cc;
      const int co = ((half * 4 + oct) ^ (cc & 7)) << 3;
      bf16x8 b = *(const bf16x8*)((const short*)Xs + p * 64 + co);
#pragma unroll
      for (int cg = 0; cg < 4; ++cg)
        acc[cg][pt] = __builtin_amdgcn_mfma_f32_16x16x32_bf16(a[cg], b, acc[cg][pt], 0, 0, 0);
    }
  }

  __syncthreads();             // all Xs reads done -> reuse as Ys
  u16* Ys = &Xs[0];            // [256 pix][64 ch], XOR swizzle on (p2&7)

  // ---- epilogue 1: x5 = acc + b2 + x ; fp32 store + bf16 stash in LDS ----
  const int b0 = f >> 3, t0 = f & 7;
  const int xresBase = (b0 * 512 + t0) * HW;
  const int outF = f * CH * HW;
#pragma unroll
  for (int cg = 0; cg < 4; ++cg)
#pragma unroll
    for (int pt = 0; pt < 4; ++pt) {
      const int lr = 2 * wv + (pt >> 1);
      const int lc = (pt & 1) * 16 + l15;
      const int p2 = lr * 32 + lc;
      const int opix = (h0 + lr) * Wd + (w0 + lc);
      u16x4 pk;
#pragma unroll
      for (int rr = 0; rr < 4; ++rr) {
        const int cout = cg * 16 + oct * 4 + rr;
        float v = acc[cg][pt][rr] + bias[cout] + xres[xresBase + cout * (TT * HW) + opix];
        outf[outF + cout * HW + opix] = v;
        pk[rr] = tobf(v);
      }
      const int unit = (cg * 2 + (oct >> 1)) ^ (p2 & 7);
      *(u16x4*)(Ys + p2 * 64 + unit * 8 + (oct & 1) * 4) = pk;
    }
  __syncthreads();

  // ---- phase 2: k = wk1 @ x5 + bk1 (2 MFMA k-steps) ----
  f32x4 acc2[4][4];
#pragma unroll
  for (int i = 0; i < 4; ++i)
#pragma unroll
    for (int j = 0; j < 4; ++j) acc2[i][j] = (f32x4)0.f;

#pragma unroll
  for (int s = 0; s < 2; ++s) {
    bf16x8 a2[4];
#pragma unroll
    for (int cg = 0; cg < 4; ++cg)
      a2[cg] = *(const bf16x8*)(w1b + (cg * 16 + l15) * 64 + s * 32 + oct * 8);
#pragma unroll
    for (int pt = 0; pt < 4; ++pt) {
      const int p2 = (2 * wv + (pt >> 1)) * 32 + (pt & 1) * 16 + l15;
      const int co = ((s * 4 + oct) ^ (p2 & 7)) << 3;
      bf16x8 b = *(const bf16x8*)((const short*)Ys + p2 * 64 + co);
#pragma unroll
      for (int cg = 0; cg < 4; ++cg)
        acc2[cg][pt] = __builtin_amdgcn_mfma_f32_16x16x32_bf16(a2[cg], b, acc2[cg][pt], 0, 0, 0);
    }
  }

#pragma unroll
  for (int cg = 0; cg < 4; ++cg)
#pragma unroll
    for (int pt = 0; pt < 4; ++pt) {
      const int py = h0 + 2 * wv + (pt >> 1);
      const int px = w0 + (pt & 1) * 16 + l15;
      const int pph = py + 1, ppw = px + 1;
      const int unit = (cg * 2 + (oct >> 1)) ^ (ppw & 7);
      u16x4 pk;
#pragma unroll
      for (int rr = 0; rr < 4; ++rr) {
        const int kout = cg * 16 + oct * 4 + rr;
        pk[rr] = tobf(acc2[cg][pt][rr] + b1x1[kout]);
      }
      *(u16x4*)(outb + ((size_t)f * PW + pph) * PW * CH + (size_t)ppw * CH +
                unit * 8 + (oct & 1) * 4) = pk;
    }
}

// stride-2 3x3 conv 64->9 from padded swizzled bf16. Output (16,9,64,64).
__global__ __launch_bounds__(256) void convs2b_k(
    const u16* __restrict__ inb, const float* __restrict__ wgt,
    const float* __restrict__ bias, float* __restrict__ out)
{
  const int f = blockIdx.y;
  const int idx = blockIdx.x * 256 + threadIdx.x;   // 4096
  const int wo = idx & 63, ho = idx >> 6;
  float acc[9];
#pragma unroll
  for (int i = 0; i < 9; ++i) acc[i] = 0.f;
#pragma unroll 1
  for (int di = 0; di < 3; ++di)
#pragma unroll 1
    for (int dj = 0; dj < 3; ++dj) {
      const int pph = 2 * ho + di, ppw = 2 * wo + dj;
      const u16* row = inb + ((size_t)f * PW + pph) * PW * CH + (size_t)ppw * CH;
      const int q = di * 3 + dj;
#pragma unroll
      for (int ub = 0; ub < 8; ++ub) {
        const int unit = ub ^ (ppw & 7);
        u16x8 pk = *(const u16x8*)(row + unit * 8);
#pragma unroll
        for (int j = 0; j < 8; ++j) {
          const float xv = bf2f(pk[j]);
          const int c = ub * 8 + j;
#pragma unroll
          for (int kk = 0; kk < 9; ++kk)
            acc[kk] = fmaf(xv, wgt[(kk * 64 + c) * 9 + q], acc[kk]);
        }
      }
    }
  const int oBase = f * 9 * 4096 + ho * 64 + wo;
#pragma unroll
  for (int kk = 0; kk < 9; ++kk) out[oBase + kk * 4096] = acc[kk] + bias[kk];
}

// softmax over 72 per (b,ho,wo). scores (16,9,64,64) -> wout (b,pix,72)
__global__ __launch_bounds__(256) void softmax_k(
    const float* __restrict__ sc, float* __restrict__ wout)
{
  const int idx = blockIdx.x * 256 + threadIdx.x;
  const int b = idx >> 12, pix = idx & 4095;
  float v[72];
  float mx = -1e30f;
#pragma unroll
  for (int t = 0; t < 8; ++t)
#pragma unroll
    for (int kk = 0; kk < 9; ++kk) {
      float s = sc[((b * 8 + t) * 9 + kk) * 4096 + pix];
      v[t * 9 + kk] = s;
      mx = fmaxf(mx, s);
    }
  float sum = 0.f;
#pragma unroll
  for (int i = 0; i < 72; ++i) { v[i] = __expf(v[i] - mx); sum += v[i]; }
  float inv = 1.f / sum;
#pragma unroll
  for (int i = 0; i < 72; ++i) wout[idx * 72 + i] = v[i] * inv;
}

// weighted patch reduce from x5 fp32 [f][c][HW].
__global__ __launch_bounds__(256) void gather_k(
    const float* __restrict__ x5, const float* __restrict__ wts,
    float* __restrict__ out)
{
  const int cgrp = blockIdx.x;
  const int ho = blockIdx.y;
  const int b = blockIdx.z;
  __shared__ float wl[64 * 73];
  const float* wsrc = &wts[(b * 4096 + ho * 64) * 72];
  for (int e = threadIdx.x; e < 64 * 72; e += 256) {
    int wo = e / 72, k = e - wo * 72;
    wl[wo * 73 + k] = wsrc[e];
  }
  __syncthreads();
  const int wo = threadIdx.x & 63;
  const int sub = threadIdx.x >> 6;
  const int hc = 2 * ho - 1, wc = 2 * wo - 1;
#pragma unroll
  for (int cc2 = 0; cc2 < 2; ++cc2) {
    const int c = cgrp * 8 + sub * 2 + cc2;
    float acc = 0.f;
#pragma unroll 1
    for (int t = 0; t < 8; ++t) {
      const int base = ((b * 8 + t) * 64 + c) * HW;
      const float* wrow = &wl[wo * 73 + t * 9];
#pragma unroll
      for (int di = 0; di < 3; ++di) {
        int h = min(max(hc + di, 0), 127);
#pragma unroll
        for (int dj = 0; dj < 3; ++dj) {
          int w = min(max(wc + dj, 0), 127);
          acc = fmaf(x5[base + h * Wd + w], wrow[di * 3 + dj], acc);
        }
      }
    }
    out[((b * 64 + c) * 64 + ho) * 64 + wo] = acc;
  }
}

extern "C" void kernel_launch(void* const* d_in, const int* in_sizes, int n_in,
                              void* d_out, int out_size, void* d_ws, size_t ws_size,
                              hipStream_t stream)
{
  const float* x   = (const float*)d_in[0];
  const float* w1  = (const float*)d_in[1];
  const float* b1  = (const float*)d_in[2];
  const float* w2  = (const float*)d_in[3];
  const float* b2  = (const float*)d_in[4];
  const float* wk1 = (const float*)d_in[5];
  const float* bk1 = (const float*)d_in[6];
  const float* wk2 = (const float*)d_in[7];
  const float* bk2 = (const float*)d_in[8];
  const float* wk3 = (const float*)d_in[9];
  const float* bk3 = (const float*)d_in[10];
  float* outp = (float*)d_out;

  const size_t PADB = (size_t)16 * PW * PW * CH * 2;   // 34,611,200 B
  char* ws = (char*)d_ws;
  float* x5     = (float*)ws;                          // 64 MB fp32 [f][c][HW]
  u16*  P1      = (u16*)(ws + 67108864);               // xbfp, then kf2
  u16*  P2      = (u16*)(ws + 67108864 + PADB);        // res1
  u16*  P3      = (u16*)(ws + 67108864 + 2 * PADB);    // k
  float* scores = (float*)(ws + 67108864 + 3 * PADB);  // 2.25 MB
  float* wbuf   = (float*)(ws + 67108864 + 3 * PADB + 2359296);
  short* Wp1    = (short*)(ws + 67108864 + 3 * PADB + 2 * 2359296);
  short* Wp2    = Wp1 + 36864;
  short* Wp4    = Wp2 + 36864;
  short* Wk1b   = Wp4 + 36864;                         // 4096 bf16
  (void)ws_size; (void)in_sizes; (void)n_in; (void)out_size;

  // allow 158KB dynamic LDS for the persistent conv (idempotent, capture-safe)
  hipFuncSetAttribute((const void*)conv3x3_pers_k,
                      hipFuncAttributeMaxDynamicSharedMemorySize, 161792);

  packw_k<<<dim3(144), 256, 0, stream>>>(w1, Wp1);
  packw_k<<<dim3(144), 256, 0, stream>>>(w2, Wp2);
  packw_k<<<dim3(144), 256, 0, stream>>>(wk2, Wp4);
  packw1_k<<<dim3(16), 256, 0, stream>>>(wk1, Wk1b);

  // x -> padded swizzled bf16 (writes pads = 0)
  xprep_k<<<dim3(16, PW), 256, 0, stream>>>(x, P1);
  // zero pad rings (interiors written by convs)
  padzero_k<<<dim3(17, 16), 256, 0, stream>>>(P2);
  padzero_k<<<dim3(17, 16), 256, 0, stream>>>(P3);

  // 1: res1 = lrelu(conv(x, w1) + b1)                    -> P2
  conv3x3_pers_k<<<dim3(256), 256, 161792, stream>>>(P1, Wp1, b1, P2);
  // 2: x5 = x + conv(res1*shift(res1), w2) + b2 (fp32);
  //    k = wk1@x5 + bk1 (bf16)                           -> x5, P3
  conv3x3_x5_k<<<dim3(4, 16, 16), 256, 0, stream>>>(P2, Wp2, b2, x, Wk1b, bk1, x5, P3);
  // 3: kf2 = lrelu(conv(k, wk2) + bk2)                   -> P1 (pads 0 from xprep)
  conv3x3_pers_k<<<dim3(256), 256, 161792, stream>>>(P3, Wp4, bk2, P1);
  // 4: scores = conv_s2(kf2, wk3) + bk3
  convs2b_k<<<dim3(16, 16), 256, 0, stream>>>(P1, wk3, bk3, scores);
  // 5: softmax over 72
  softmax_k<<<dim3(32), 256, 0, stream>>>(scores, wbuf);
  // 6: weighted gather
  gather_k<<<dim3(8, 64, 2), 256, 0, stream>>>(x5, wbuf, outp);
}

// Round 8
// 248.125 us; speedup vs baseline: 17.0220x; 1.0570x over previous
//
#include <hip/hip_runtime.h>
#include <hip/hip_bf16.h>
#include <math.h>

#define Wd 128
#define Hd 128
#define HW 16384
#define CH 64
#define TT 8
#define NEGS 0.2f
#define PW 130                    // padded width/height
#define ROWB (PW * CH * 2)        // padded row bytes = 16640

typedef unsigned short u16;
typedef u16 u16x8 __attribute__((ext_vector_type(8)));
typedef u16 u16x4 __attribute__((ext_vector_type(4)));
typedef short bf16x8 __attribute__((ext_vector_type(8)));
typedef float f32x4 __attribute__((ext_vector_type(4)));

__device__ __forceinline__ u16 tobf(float v) {
  __hip_bfloat16 h = __float2bfloat16(v);
  return __builtin_bit_cast(u16, h);
}
__device__ __forceinline__ float bf2f(u16 u) {
  unsigned x = ((unsigned)u) << 16;
  return __builtin_bit_cast(float, x);
}
__device__ __forceinline__ void gload_lds16(const void* g, void* l) {
  __builtin_amdgcn_global_load_lds(
      (const __attribute__((address_space(1))) unsigned int*)g,
      (__attribute__((address_space(3))) unsigned int*)l, 16, 0, 0);
}

// Pack 3x3 weights fp32 -> bf16 [cout][k] with granule XOR swizzle.
__global__ __launch_bounds__(256) void packw_k(const float* __restrict__ w,
                                               short* __restrict__ out)
{
  int i = blockIdx.x * 256 + threadIdx.x;       // 36864
  int cout = i / 576, k = i - cout * 576;
  int off = k >> 6, cin = k & 63;
  int dy = off / 3, dx = off - dy * 3;
  int gi = cout * 72 + (k >> 3);
  int go = ((gi ^ (cout & 7)) << 3) + (k & 7);
  out[go] = (short)tobf(w[((cout * 64 + cin) * 3 + dy) * 3 + dx]);
}

// Pack 1x1 weights (64,64) fp32 -> bf16 row-major [kout][cin] (linear).
__global__ __launch_bounds__(256) void packw1_k(const float* __restrict__ w,
                                                short* __restrict__ out)
{
  int i = blockIdx.x * 256 + threadIdx.x;       // 4096
  out[i] = (short)tobf(w[i]);
}

// x (B,C,T,H,W) fp32 -> padded swizzled bf16 [f][130][130][64].
__global__ __launch_bounds__(256) void xprep_k(const float* __restrict__ x,
                                               u16* __restrict__ outb)
{
  const int f = blockIdx.x, b = f >> 3, t = f & 7;
  const int ph = blockIdx.y;                    // 0..129
  const int u = threadIdx.x & 7;
  const int p0 = threadIdx.x >> 3;              // 0..31
#pragma unroll
  for (int i = 0; i < 5; ++i) {
    const int ppw = p0 + 32 * i;
    if (ppw < PW) {
      const int cb = (u ^ (ppw & 7)) << 3;
      const int h = ph - 1, w = ppw - 1;
      u16x8 pk = (u16x8)0;
      if (h >= 0 && h < Hd && w >= 0 && w < Wd) {
        const float* src = x + (((size_t)(b * 64 + cb) * 8 + t) * HW) + h * Wd + w;
#pragma unroll
        for (int j = 0; j < 8; ++j) pk[j] = tobf(src[(size_t)j * 8 * HW]);
      }
      *(u16x8*)(outb + ((size_t)f * PW + ph) * PW * CH + (size_t)ppw * CH + u * 8) = pk;
    }
  }
}

// Zero the 1-pixel pad ring of a padded bf16 buffer (all 16 frames).
__global__ __launch_bounds__(256) void padzero_k(u16* __restrict__ buf)
{
  const int f = blockIdx.y;
  u16* fb = buf + (size_t)f * PW * PW * CH;
  const int g = blockIdx.x * 256 + threadIdx.x;
  if (g >= 4128) return;
  size_t off;
  if (g < 1040)      off = (size_t)g * 8;
  else if (g < 2080) off = (size_t)129 * PW * CH + (size_t)(g - 1040) * 8;
  else if (g < 3104) { int r = (g - 2080) >> 3, u = (g - 2080) & 7;
                       off = ((size_t)(r + 1) * PW + 0) * CH + u * 8; }
  else               { int r = (g - 3104) >> 3, u = (g - 3104) & 7;
                       off = ((size_t)(r + 1) * PW + 129) * CH + u * 8; }
  *(u16x8*)(fb + off) = (u16x8)0;
}

// Persistent double-buffered 3x3 conv 64->64 via bf16 MFMA + lrelu.
__global__ __launch_bounds__(256) void conv3x3_pers_k(
    const u16* __restrict__ inp, const short* __restrict__ wsw,
    const float* __restrict__ bias, u16* __restrict__ outb)
{
  extern __shared__ __align__(16) char smem[];
  short* Ws = (short*)smem;                          // 73728 B
  u16* Xb0 = (u16*)(smem + 73728);                   // 44032 B
  u16* Xb1 = (u16*)(smem + 73728 + 44032);           // 44032 B

  const int bid = blockIdx.x;
  const int f = bid >> 4, hy = bid & 15;
  const int h0 = hy * 8;
  const int tid = threadIdx.x;
  const int lane = tid & 63;
  const int wv = __builtin_amdgcn_readfirstlane(tid >> 6);
  const int l15 = lane & 15;
  const int oct = lane >> 4;

  f32x4 b4[4];
#pragma unroll
  for (int cg = 0; cg < 4; ++cg)
#pragma unroll
    for (int rr = 0; rr < 4; ++rr)
      b4[cg][rr] = bias[cg * 16 + oct * 4 + rr];

  {
    const char* gs = (const char*)wsw;
    char* ld = (char*)Ws;
#pragma unroll 1
    for (int i = wv; i < 72; i += 4)
      gload_lds16(gs + i * 1024 + lane * 16, ld + i * 1024);
  }

  const char* fbp = (const char*)(inp + (size_t)f * PW * PW * CH);

  {
    const char* tb = fbp + (size_t)h0 * ROWB;
    char* ld = (char*)Xb0;
#pragma unroll 1
    for (int i = wv; i < 43; i += 4) {
      const int ob = i * 1024 + lane * 16;
      const int row = ob / 4352;
      const int rem = ob - row * 4352;
      gload_lds16(tb + (size_t)row * ROWB + rem, ld + i * 1024);
    }
  }

#pragma unroll 1
  for (int it = 0; it < 4; ++it) {
    __syncthreads();
    u16* Xc = (it & 1) ? Xb1 : Xb0;
    u16* Xn = (it & 1) ? Xb0 : Xb1;
    if (it < 3) {
      const char* tb = fbp + (size_t)h0 * ROWB + (size_t)(it + 1) * 32 * CH * 2;
      char* ld = (char*)Xn;
#pragma unroll 1
      for (int i = wv; i < 43; i += 4) {
        const int ob = i * 1024 + lane * 16;
        const int row = ob / 4352;
        const int rem = ob - row * 4352;
        gload_lds16(tb + (size_t)row * ROWB + rem, ld + i * 1024);
      }
    }
    const int w0 = it * 32;

    f32x4 acc[4][4];
#pragma unroll
    for (int i = 0; i < 4; ++i)
#pragma unroll
      for (int j = 0; j < 4; ++j) acc[i][j] = (f32x4)0.f;

#pragma unroll 1
    for (int s = 0; s < 18; ++s) {
      const int o = s >> 1;
      const int dy = o / 3, dx = o - dy * 3;
      const int half = s & 1;
      bf16x8 a[4];
#pragma unroll
      for (int cg = 0; cg < 4; ++cg) {
        const int gi = (cg * 16 + l15) * 72 + s * 4 + oct;
        a[cg] = *(const bf16x8*)(Ws + ((gi ^ (l15 & 7)) << 3));
      }
#pragma unroll
      for (int pt = 0; pt < 4; ++pt) {
        const int r = 2 * wv + (pt >> 1) + dy;
        const int cc = (pt & 1) * 16 + dx + l15;
        const int p = r * 34 + cc;
        const int co = ((half * 4 + oct) ^ (cc & 7)) << 3;
        bf16x8 b = *(const bf16x8*)((const short*)Xc + p * 64 + co);
#pragma unroll
        for (int cg = 0; cg < 4; ++cg)
          acc[cg][pt] = __builtin_amdgcn_mfma_f32_16x16x32_bf16(a[cg], b, acc[cg][pt], 0, 0, 0);
      }
    }

#pragma unroll
    for (int cg = 0; cg < 4; ++cg)
#pragma unroll
      for (int pt = 0; pt < 4; ++pt) {
        const int py = h0 + 2 * wv + (pt >> 1);
        const int px = w0 + (pt & 1) * 16 + l15;
        const int pph = py + 1, ppw = px + 1;
        const int unit = (cg * 2 + (oct >> 1)) ^ (ppw & 7);
        u16x4 pk;
#pragma unroll
        for (int rr = 0; rr < 4; ++rr) {
          float t2 = acc[cg][pt][rr] + b4[cg][rr];
          t2 = (t2 >= 0.f) ? t2 : NEGS * t2;
          pk[rr] = tobf(t2);
        }
        *(u16x4*)(outb + ((size_t)f * PW + pph) * PW * CH + (size_t)ppw * CH +
                  unit * 8 + (oct & 1) * 4) = pk;
      }
  }
}

// Fused: sm = res1*shift(res1) during staging; x5 = x + conv3x3(sm,w2) + b2
// (padded swizzled BF16 out — single tensor, consumed by gather);
// k = wk1 @ x5 + bk1 (bf16 padded swizzled out) via LDS round-trip.
__global__ __launch_bounds__(256) void conv3x3_x5_k(
    const u16* __restrict__ inp, const short* __restrict__ wb,
    const float* __restrict__ bias, const float* __restrict__ xres,
    const short* __restrict__ w1b, const float* __restrict__ b1x1,
    u16* __restrict__ outx, u16* __restrict__ outb)
{
  const int f = blockIdx.z;
  const int h0 = blockIdx.y * 8;
  const int w0 = blockIdx.x * 32;
  const int tid = threadIdx.x;
  const int lane = tid & 63;
  const int wv = __builtin_amdgcn_readfirstlane(tid >> 6);
  const int l15 = lane & 15;
  const int oct = lane >> 4;

  __shared__ __align__(16) u16 Xs[340 * 64];

  // ---- fused shift-mul staging (unrolled for load overlap) ----
  const size_t fbase = (size_t)f * PW * PW * CH;
#pragma unroll 2
  for (int e = tid; e < 2720; e += 256) {
    const int us = e & 7;
    const int pix = e >> 3;
    const int r = pix / 34;
    const int cc = pix - r * 34;
    const int ph = h0 + r;
    const int ppw = w0 + cc;
    const int ub = us ^ (cc & 7);
    const int g = ub >> 1;
    const int dw = (g == 0) ? -4 : (g == 1) ? 4 : 0;
    const int dh = (g == 2) ? -4 : (g == 3) ? 4 : 0;
    u16x8 v = *(const u16x8*)(inp + fbase + ((size_t)ph * PW + ppw) * CH + us * 8);
    const int h2 = ph + dh, w2 = ppw + dw;
    const bool okp = (h2 >= 1 && h2 <= Hd && w2 >= 1 && w2 <= Wd);
    const int h2c = min(max(h2, 0), PW - 1);
    const int w2c = min(max(w2, 0), PW - 1);
    const int u2 = (dw != 0) ? (us ^ 4) : us;
    u16x8 pv = *(const u16x8*)(inp + fbase + ((size_t)h2c * PW + w2c) * CH + u2 * 8);
    u16x8 o;
#pragma unroll
    for (int j = 0; j < 8; ++j) {
      float pr = okp ? bf2f(v[j]) * bf2f(pv[j]) : 0.f;
      o[j] = tobf(pr);
    }
    *(u16x8*)((u16*)Xs + pix * 64 + us * 8) = o;
  }
  __syncthreads();

  f32x4 acc[4][4];
#pragma unroll
  for (int i = 0; i < 4; ++i)
#pragma unroll
    for (int j = 0; j < 4; ++j) acc[i][j] = (f32x4)0.f;

#pragma unroll 1
  for (int s = 0; s < 18; ++s) {
    const int o = s >> 1;
    const int dy = o / 3, dx = o - dy * 3;
    const int half = s & 1;
    bf16x8 a[4];
#pragma unroll
    for (int cg = 0; cg < 4; ++cg) {
      const int gi = (cg * 16 + l15) * 72 + s * 4 + oct;
      a[cg] = *(const bf16x8*)(wb + ((gi ^ (l15 & 7)) << 3));
    }
#pragma unroll
    for (int pt = 0; pt < 4; ++pt) {
      const int r = 2 * wv + (pt >> 1) + dy;
      const int cc = (pt & 1) * 16 + dx + l15;
      const int p = r * 34 + cc;
      const int co = ((half * 4 + oct) ^ (cc & 7)) << 3;
      bf16x8 b = *(const bf16x8*)((const short*)Xs + p * 64 + co);
#pragma unroll
      for (int cg = 0; cg < 4; ++cg)
        acc[cg][pt] = __builtin_amdgcn_mfma_f32_16x16x32_bf16(a[cg], b, acc[cg][pt], 0, 0, 0);
    }
  }

  __syncthreads();             // Xs reads done -> reuse as Ys
  u16* Ys = &Xs[0];            // [256 pix][64 ch], XOR swizzle on (p2&7)

  // ---- epilogue 1: x5 = acc + b2 + x -> bf16 padded store + Ys stash ----
  const int b0 = f >> 3, t0 = f & 7;
  const int xresBase = (b0 * 512 + t0) * HW;
#pragma unroll
  for (int cg = 0; cg < 4; ++cg)
#pragma unroll
    for (int pt = 0; pt < 4; ++pt) {
      const int lr = 2 * wv + (pt >> 1);
      const int lc = (pt & 1) * 16 + l15;
      const int p2 = lr * 32 + lc;
      const int opix = (h0 + lr) * Wd + (w0 + lc);
      u16x4 pk;
#pragma unroll
      for (int rr = 0; rr < 4; ++rr) {
        const int cout = cg * 16 + oct * 4 + rr;
        float v = acc[cg][pt][rr] + bias[cout] + xres[xresBase + cout * (TT * HW) + opix];
        pk[rr] = tobf(v);
      }
      const int pph = h0 + lr + 1, ppw = w0 + lc + 1;
      const int unitg = (cg * 2 + (oct >> 1)) ^ (ppw & 7);
      *(u16x4*)(outx + ((size_t)f * PW + pph) * PW * CH + (size_t)ppw * CH +
                unitg * 8 + (oct & 1) * 4) = pk;
      const int unit2 = (cg * 2 + (oct >> 1)) ^ (p2 & 7);
      *(u16x4*)(Ys + p2 * 64 + unit2 * 8 + (oct & 1) * 4) = pk;
    }
  __syncthreads();

  // ---- phase 2: k = wk1 @ x5 + bk1 (2 MFMA k-steps) ----
  f32x4 acc2[4][4];
#pragma unroll
  for (int i = 0; i < 4; ++i)
#pragma unroll
    for (int j = 0; j < 4; ++j) acc2[i][j] = (f32x4)0.f;

#pragma unroll
  for (int s = 0; s < 2; ++s) {
    bf16x8 a2[4];
#pragma unroll
    for (int cg = 0; cg < 4; ++cg)
      a2[cg] = *(const bf16x8*)(w1b + (cg * 16 + l15) * 64 + s * 32 + oct * 8);
#pragma unroll
    for (int pt = 0; pt < 4; ++pt) {
      const int p2 = (2 * wv + (pt >> 1)) * 32 + (pt & 1) * 16 + l15;
      const int co = ((s * 4 + oct) ^ (p2 & 7)) << 3;
      bf16x8 b = *(const bf16x8*)((const short*)Ys + p2 * 64 + co);
#pragma unroll
      for (int cg = 0; cg < 4; ++cg)
        acc2[cg][pt] = __builtin_amdgcn_mfma_f32_16x16x32_bf16(a2[cg], b, acc2[cg][pt], 0, 0, 0);
    }
  }

#pragma unroll
  for (int cg = 0; cg < 4; ++cg)
#pragma unroll
    for (int pt = 0; pt < 4; ++pt) {
      const int py = h0 + 2 * wv + (pt >> 1);
      const int px = w0 + (pt & 1) * 16 + l15;
      const int pph = py + 1, ppw = px + 1;
      const int unit = (cg * 2 + (oct >> 1)) ^ (ppw & 7);
      u16x4 pk;
#pragma unroll
      for (int rr = 0; rr < 4; ++rr) {
        const int kout = cg * 16 + oct * 4 + rr;
        pk[rr] = tobf(acc2[cg][pt][rr] + b1x1[kout]);
      }
      *(u16x4*)(outb + ((size_t)f * PW + pph) * PW * CH + (size_t)ppw * CH +
                unit * 8 + (oct & 1) * 4) = pk;
    }
}

// stride-2 3x3 conv 64->9 from padded swizzled bf16. Output (16,9,64,64).
__global__ __launch_bounds__(256) void convs2b_k(
    const u16* __restrict__ inb, const float* __restrict__ wgt,
    const float* __restrict__ bias, float* __restrict__ out)
{
  const int f = blockIdx.y;
  const int idx = blockIdx.x * 256 + threadIdx.x;   // 4096
  const int wo = idx & 63, ho = idx >> 6;
  float acc[9];
#pragma unroll
  for (int i = 0; i < 9; ++i) acc[i] = 0.f;
#pragma unroll 1
  for (int di = 0; di < 3; ++di)
#pragma unroll 1
    for (int dj = 0; dj < 3; ++dj) {
      const int pph = 2 * ho + di, ppw = 2 * wo + dj;
      const u16* row = inb + ((size_t)f * PW + pph) * PW * CH + (size_t)ppw * CH;
      const int q = di * 3 + dj;
#pragma unroll
      for (int ub = 0; ub < 8; ++ub) {
        const int unit = ub ^ (ppw & 7);
        u16x8 pk = *(const u16x8*)(row + unit * 8);
#pragma unroll
        for (int j = 0; j < 8; ++j) {
          const float xv = bf2f(pk[j]);
          const int c = ub * 8 + j;
#pragma unroll
          for (int kk = 0; kk < 9; ++kk)
            acc[kk] = fmaf(xv, wgt[(kk * 64 + c) * 9 + q], acc[kk]);
        }
      }
    }
  const int oBase = f * 9 * 4096 + ho * 64 + wo;
#pragma unroll
  for (int kk = 0; kk < 9; ++kk) out[oBase + kk * 4096] = acc[kk] + bias[kk];
}

// softmax over 72 per (b,ho,wo). scores (16,9,64,64) -> wout (b,pix,72)
__global__ __launch_bounds__(256) void softmax_k(
    const float* __restrict__ sc, float* __restrict__ wout)
{
  const int idx = blockIdx.x * 256 + threadIdx.x;
  const int b = idx >> 12, pix = idx & 4095;
  float v[72];
  float mx = -1e30f;
#pragma unroll
  for (int t = 0; t < 8; ++t)
#pragma unroll
    for (int kk = 0; kk < 9; ++kk) {
      float s = sc[((b * 8 + t) * 9 + kk) * 4096 + pix];
      v[t * 9 + kk] = s;
      mx = fmaxf(mx, s);
    }
  float sum = 0.f;
#pragma unroll
  for (int i = 0; i < 72; ++i) { v[i] = __expf(v[i] - mx); sum += v[i]; }
  float inv = 1.f / sum;
#pragma unroll
  for (int i = 0; i < 72; ++i) wout[idx * 72 + i] = v[i] * inv;
}

// weighted patch reduce from PADDED SWIZZLED BF16 x5 (channel-vectorized).
// lane = octet u (8 ch) x wo_lo; each u16x8 load = 8 channels, 1KB/wave-instr.
__global__ __launch_bounds__(256) void gather2_k(
    const u16* __restrict__ x5p, const float* __restrict__ wts,
    float* __restrict__ out)
{
  const int hx = blockIdx.x;       // wo half (0..1)
  const int ho = blockIdx.y;       // 0..63
  const int b  = blockIdx.z;       // 0..1
  const int wo0 = hx * 32;
  __shared__ float wl[32 * 73];
  const float* wsrc = &wts[((size_t)b * 4096 + (size_t)ho * 64 + wo0) * 72];
  for (int e = threadIdx.x; e < 32 * 72; e += 256) {
    int wo = e / 72, k = e - wo * 72;
    wl[wo * 73 + k] = wsrc[e];
  }
  __syncthreads();
  const int lane = threadIdx.x & 63;
  const int wv = threadIdx.x >> 6;
  const int u = lane & 7;                 // channel octet
  const int wol = (lane >> 3) + wv * 8;   // 0..31
  const int wo = wo0 + wol;
  float acc[8];
#pragma unroll
  for (int j = 0; j < 8; ++j) acc[j] = 0.f;
#pragma unroll 1
  for (int t = 0; t < 8; ++t) {
    const int f = b * 8 + t;
    const size_t fb = (size_t)f * PW * PW * CH;
    const float* wrow = &wl[wol * 73 + t * 9];
#pragma unroll
    for (int di = 0; di < 3; ++di) {
      const int pph = min(max(2 * ho + di, 1), 128);
#pragma unroll
      for (int dj = 0; dj < 3; ++dj) {
        const int ppw = min(max(2 * wo + dj, 1), 128);
        const int unit = u ^ (ppw & 7);
        u16x8 pk = *(const u16x8*)(x5p + fb + ((size_t)pph * PW + ppw) * CH + unit * 8);
        const float wq = wrow[di * 3 + dj];
#pragma unroll
        for (int j = 0; j < 8; ++j)
          acc[j] = fmaf(bf2f(pk[j]), wq, acc[j]);
      }
    }
  }
  const int obase = ((b * 64 + u * 8) * 64 + ho) * 64 + wo;
#pragma unroll
  for (int j = 0; j < 8; ++j)
    out[obase + j * 4096] = acc[j];
}

extern "C" void kernel_launch(void* const* d_in, const int* in_sizes, int n_in,
                              void* d_out, int out_size, void* d_ws, size_t ws_size,
                              hipStream_t stream)
{
  const float* x   = (const float*)d_in[0];
  const float* w1  = (const float*)d_in[1];
  const float* b1  = (const float*)d_in[2];
  const float* w2  = (const float*)d_in[3];
  const float* b2  = (const float*)d_in[4];
  const float* wk1 = (const float*)d_in[5];
  const float* bk1 = (const float*)d_in[6];
  const float* wk2 = (const float*)d_in[7];
  const float* bk2 = (const float*)d_in[8];
  const float* wk3 = (const float*)d_in[9];
  const float* bk3 = (const float*)d_in[10];
  float* outp = (float*)d_out;

  const size_t PADB = (size_t)16 * PW * PW * CH * 2;   // 34,611,200 B
  char* ws = (char*)d_ws;
  u16*  P1      = (u16*)ws;                            // x bf16, then kf2
  u16*  P2      = (u16*)(ws + PADB);                   // res1
  u16*  P3      = (u16*)(ws + 2 * PADB);               // k
  u16*  P4      = (u16*)(ws + 3 * PADB);               // x5 bf16
  float* scores = (float*)(ws + 4 * PADB);             // 2.25 MB
  float* wbuf   = (float*)(ws + 4 * PADB + 2359296);
  short* Wp1    = (short*)(ws + 4 * PADB + 2 * 2359296);
  short* Wp2    = Wp1 + 36864;
  short* Wp4    = Wp2 + 36864;
  short* Wk1b   = Wp4 + 36864;                         // 4096 bf16
  (void)ws_size; (void)in_sizes; (void)n_in; (void)out_size;

  hipFuncSetAttribute((const void*)conv3x3_pers_k,
                      hipFuncAttributeMaxDynamicSharedMemorySize, 161792);

  packw_k<<<dim3(144), 256, 0, stream>>>(w1, Wp1);
  packw_k<<<dim3(144), 256, 0, stream>>>(w2, Wp2);
  packw_k<<<dim3(144), 256, 0, stream>>>(wk2, Wp4);
  packw1_k<<<dim3(16), 256, 0, stream>>>(wk1, Wk1b);

  // x -> padded swizzled bf16 (ring = 0)
  xprep_k<<<dim3(16, PW), 256, 0, stream>>>(x, P1);
  // zero pad rings for res1 and k
  padzero_k<<<dim3(17, 16), 256, 0, stream>>>(P2);
  padzero_k<<<dim3(17, 16), 256, 0, stream>>>(P3);

  // 1: res1 = lrelu(conv(x, w1) + b1)                    -> P2
  conv3x3_pers_k<<<dim3(256), 256, 161792, stream>>>(P1, Wp1, b1, P2);
  // 2: x5 = x + conv(res1*shift(res1), w2) + b2 (bf16 padded) -> P4;
  //    k = wk1@x5 + bk1 (bf16 padded)                    -> P3
  conv3x3_x5_k<<<dim3(4, 16, 16), 256, 0, stream>>>(P2, Wp2, b2, x, Wk1b, bk1, P4, P3);
  // 3: kf2 = lrelu(conv(k, wk2) + bk2)                   -> P1 (ring 0 from xprep)
  conv3x3_pers_k<<<dim3(256), 256, 161792, stream>>>(P3, Wp4, bk2, P1);
  // 4: scores = conv_s2(kf2, wk3) + bk3
  convs2b_k<<<dim3(16, 16), 256, 0, stream>>>(P1, wk3, bk3, scores);
  // 5: softmax over 72
  softmax_k<<<dim3(32), 256, 0, stream>>>(scores, wbuf);
  // 6: weighted gather (bf16 x5)
  gather2_k<<<dim3(2, 64, 2), 256, 0, stream>>>(P4, wbuf, outp);
}

// Round 9
// 220.376 us; speedup vs baseline: 19.1653x; 1.1259x over previous
//
#include <hip/hip_runtime.h>
#include <hip/hip_bf16.h>
#include <math.h>

#define Wd 128
#define Hd 128
#define HW 16384
#define CH 64
#define TT 8
#define NEGS 0.2f
#define PW 130                    // padded width/height
#define ROWB (PW * CH * 2)        // padded row bytes = 16640

typedef unsigned short u16;
typedef u16 u16x8 __attribute__((ext_vector_type(8)));
typedef u16 u16x4 __attribute__((ext_vector_type(4)));
typedef short bf16x8 __attribute__((ext_vector_type(8)));
typedef float f32x4 __attribute__((ext_vector_type(4)));

__device__ __forceinline__ u16 tobf(float v) {
  __hip_bfloat16 h = __float2bfloat16(v);
  return __builtin_bit_cast(u16, h);
}
__device__ __forceinline__ float bf2f(u16 u) {
  unsigned x = ((unsigned)u) << 16;
  return __builtin_bit_cast(float, x);
}
__device__ __forceinline__ void gload_lds16(const void* g, void* l) {
  __builtin_amdgcn_global_load_lds(
      (const __attribute__((address_space(1))) unsigned int*)g,
      (__attribute__((address_space(3))) unsigned int*)l, 16, 0, 0);
}

// Pack 3x3 weights fp32 -> bf16 [cout][k] with granule XOR swizzle.
__global__ __launch_bounds__(256) void packw_k(const float* __restrict__ w,
                                               short* __restrict__ out)
{
  int i = blockIdx.x * 256 + threadIdx.x;       // 36864
  int cout = i / 576, k = i - cout * 576;
  int off = k >> 6, cin = k & 63;
  int dy = off / 3, dx = off - dy * 3;
  int gi = cout * 72 + (k >> 3);
  int go = ((gi ^ (cout & 7)) << 3) + (k & 7);
  out[go] = (short)tobf(w[((cout * 64 + cin) * 3 + dy) * 3 + dx]);
}

// Pack 1x1 weights (64,64) fp32 -> bf16 row-major [kout][cin] (linear).
__global__ __launch_bounds__(256) void packw1_k(const float* __restrict__ w,
                                                short* __restrict__ out)
{
  int i = blockIdx.x * 256 + threadIdx.x;       // 4096
  out[i] = (short)tobf(w[i]);
}

// x (B,C,T,H,W) fp32 -> padded swizzled bf16 [f][130][130][64].
__global__ __launch_bounds__(256) void xprep_k(const float* __restrict__ x,
                                               u16* __restrict__ outb)
{
  const int f = blockIdx.x, b = f >> 3, t = f & 7;
  const int ph = blockIdx.y;                    // 0..129
  const int u = threadIdx.x & 7;
  const int p0 = threadIdx.x >> 3;              // 0..31
#pragma unroll
  for (int i = 0; i < 5; ++i) {
    const int ppw = p0 + 32 * i;
    if (ppw < PW) {
      const int cb = (u ^ (ppw & 7)) << 3;
      const int h = ph - 1, w = ppw - 1;
      u16x8 pk = (u16x8)0;
      if (h >= 0 && h < Hd && w >= 0 && w < Wd) {
        const float* src = x + (((size_t)(b * 64 + cb) * 8 + t) * HW) + h * Wd + w;
#pragma unroll
        for (int j = 0; j < 8; ++j) pk[j] = tobf(src[(size_t)j * 8 * HW]);
      }
      *(u16x8*)(outb + ((size_t)f * PW + ph) * PW * CH + (size_t)ppw * CH + u * 8) = pk;
    }
  }
}

// Zero the 1-pixel pad ring of a padded bf16 buffer (all 16 frames).
__global__ __launch_bounds__(256) void padzero_k(u16* __restrict__ buf)
{
  const int f = blockIdx.y;
  u16* fb = buf + (size_t)f * PW * PW * CH;
  const int g = blockIdx.x * 256 + threadIdx.x;
  if (g >= 4128) return;
  size_t off;
  if (g < 1040)      off = (size_t)g * 8;
  else if (g < 2080) off = (size_t)129 * PW * CH + (size_t)(g - 1040) * 8;
  else if (g < 3104) { int r = (g - 2080) >> 3, u = (g - 2080) & 7;
                       off = ((size_t)(r + 1) * PW + 0) * CH + u * 8; }
  else               { int r = (g - 3104) >> 3, u = (g - 3104) & 7;
                       off = ((size_t)(r + 1) * PW + 129) * CH + u * 8; }
  *(u16x8*)(fb + off) = (u16x8)0;
}

// Persistent double-buffered 3x3 conv 64->64 via bf16 MFMA + lrelu.
// 512 threads (8 waves): each wave owns 64cout x 32pix (1 row of the 8-row
// stripe). 8 waves/CU (vs 4 in R7) doubles latency hiding at same LDS.
__global__ __launch_bounds__(512) void conv3x3_pers_k(
    const u16* __restrict__ inp, const short* __restrict__ wsw,
    const float* __restrict__ bias, u16* __restrict__ outb)
{
  extern __shared__ __align__(16) char smem[];
  short* Ws = (short*)smem;                          // 73728 B
  u16* Xb0 = (u16*)(smem + 73728);                   // 44032 B
  u16* Xb1 = (u16*)(smem + 73728 + 44032);           // 44032 B

  const int bid = blockIdx.x;
  const int f = bid >> 4, hy = bid & 15;
  const int h0 = hy * 8;
  const int tid = threadIdx.x;
  const int lane = tid & 63;
  const int wv = __builtin_amdgcn_readfirstlane(tid >> 6);  // 0..7
  const int l15 = lane & 15;
  const int oct = lane >> 4;

  f32x4 b4[4];
#pragma unroll
  for (int cg = 0; cg < 4; ++cg)
#pragma unroll
    for (int rr = 0; rr < 4; ++rr)
      b4[cg][rr] = bias[cg * 16 + oct * 4 + rr];

  {
    const char* gs = (const char*)wsw;
    char* ld = (char*)Ws;
#pragma unroll 1
    for (int i = wv; i < 72; i += 8)
      gload_lds16(gs + i * 1024 + lane * 16, ld + i * 1024);
  }

  const char* fbp = (const char*)(inp + (size_t)f * PW * PW * CH);

  {
    const char* tb = fbp + (size_t)h0 * ROWB;
    char* ld = (char*)Xb0;
#pragma unroll 1
    for (int i = wv; i < 43; i += 8) {
      const int ob = i * 1024 + lane * 16;
      const int row = ob / 4352;
      const int rem = ob - row * 4352;
      gload_lds16(tb + (size_t)row * ROWB + rem, ld + i * 1024);
    }
  }

#pragma unroll 1
  for (int it = 0; it < 4; ++it) {
    __syncthreads();
    u16* Xc = (it & 1) ? Xb1 : Xb0;
    u16* Xn = (it & 1) ? Xb0 : Xb1;
    if (it < 3) {
      const char* tb = fbp + (size_t)h0 * ROWB + (size_t)(it + 1) * 32 * CH * 2;
      char* ld = (char*)Xn;
#pragma unroll 1
      for (int i = wv; i < 43; i += 8) {
        const int ob = i * 1024 + lane * 16;
        const int row = ob / 4352;
        const int rem = ob - row * 4352;
        gload_lds16(tb + (size_t)row * ROWB + rem, ld + i * 1024);
      }
    }
    const int w0 = it * 32;

    f32x4 acc[4][2];
#pragma unroll
    for (int i = 0; i < 4; ++i)
#pragma unroll
      for (int j = 0; j < 2; ++j) acc[i][j] = (f32x4)0.f;

#pragma unroll 1
    for (int s = 0; s < 18; ++s) {
      const int o = s >> 1;
      const int dy = o / 3, dx = o - dy * 3;
      const int half = s & 1;
      bf16x8 a[4];
#pragma unroll
      for (int cg = 0; cg < 4; ++cg) {
        const int gi = (cg * 16 + l15) * 72 + s * 4 + oct;
        a[cg] = *(const bf16x8*)(Ws + ((gi ^ (l15 & 7)) << 3));
      }
#pragma unroll
      for (int pt = 0; pt < 2; ++pt) {
        const int r = wv + dy;
        const int cc = pt * 16 + dx + l15;
        const int p = r * 34 + cc;
        const int co = ((half * 4 + oct) ^ (cc & 7)) << 3;
        bf16x8 b = *(const bf16x8*)((const short*)Xc + p * 64 + co);
#pragma unroll
        for (int cg = 0; cg < 4; ++cg)
          acc[cg][pt] = __builtin_amdgcn_mfma_f32_16x16x32_bf16(a[cg], b, acc[cg][pt], 0, 0, 0);
      }
    }

#pragma unroll
    for (int cg = 0; cg < 4; ++cg)
#pragma unroll
      for (int pt = 0; pt < 2; ++pt) {
        const int py = h0 + wv;
        const int px = w0 + pt * 16 + l15;
        const int pph = py + 1, ppw = px + 1;
        const int unit = (cg * 2 + (oct >> 1)) ^ (ppw & 7);
        u16x4 pk;
#pragma unroll
        for (int rr = 0; rr < 4; ++rr) {
          float t2 = acc[cg][pt][rr] + b4[cg][rr];
          t2 = (t2 >= 0.f) ? t2 : NEGS * t2;
          pk[rr] = tobf(t2);
        }
        *(u16x4*)(outb + ((size_t)f * PW + pph) * PW * CH + (size_t)ppw * CH +
                  unit * 8 + (oct & 1) * 4) = pk;
      }
  }
}

// Fused: sm = res1*shift(res1) during staging; x5 = x + conv3x3(sm,w2) + b2
// (bf16 padded out; residual x read from BF16 padded copy - same layout);
// k = wk1 @ x5 + bk1 (bf16 padded out) via LDS round-trip.
__global__ __launch_bounds__(256) void conv3x3_x5_k(
    const u16* __restrict__ inp, const short* __restrict__ wb,
    const float* __restrict__ bias, const u16* __restrict__ xp,
    const short* __restrict__ w1b, const float* __restrict__ b1x1,
    u16* __restrict__ outx, u16* __restrict__ outb)
{
  const int f = blockIdx.z;
  const int h0 = blockIdx.y * 8;
  const int w0 = blockIdx.x * 32;
  const int tid = threadIdx.x;
  const int lane = tid & 63;
  const int wv = __builtin_amdgcn_readfirstlane(tid >> 6);
  const int l15 = lane & 15;
  const int oct = lane >> 4;

  __shared__ __align__(16) u16 Xs[340 * 64];

  // ---- fused shift-mul staging ----
  const size_t fbase = (size_t)f * PW * PW * CH;
#pragma unroll 2
  for (int e = tid; e < 2720; e += 256) {
    const int us = e & 7;
    const int pix = e >> 3;
    const int r = pix / 34;
    const int cc = pix - r * 34;
    const int ph = h0 + r;
    const int ppw = w0 + cc;
    const int ub = us ^ (cc & 7);
    const int g = ub >> 1;
    const int dw = (g == 0) ? -4 : (g == 1) ? 4 : 0;
    const int dh = (g == 2) ? -4 : (g == 3) ? 4 : 0;
    u16x8 v = *(const u16x8*)(inp + fbase + ((size_t)ph * PW + ppw) * CH + us * 8);
    const int h2 = ph + dh, w2 = ppw + dw;
    const bool okp = (h2 >= 1 && h2 <= Hd && w2 >= 1 && w2 <= Wd);
    const int h2c = min(max(h2, 0), PW - 1);
    const int w2c = min(max(w2, 0), PW - 1);
    const int u2 = (dw != 0) ? (us ^ 4) : us;
    u16x8 pv = *(const u16x8*)(inp + fbase + ((size_t)h2c * PW + w2c) * CH + u2 * 8);
    u16x8 o;
#pragma unroll
    for (int j = 0; j < 8; ++j) {
      float pr = okp ? bf2f(v[j]) * bf2f(pv[j]) : 0.f;
      o[j] = tobf(pr);
    }
    *(u16x8*)((u16*)Xs + pix * 64 + us * 8) = o;
  }
  __syncthreads();

  f32x4 acc[4][4];
#pragma unroll
  for (int i = 0; i < 4; ++i)
#pragma unroll
    for (int j = 0; j < 4; ++j) acc[i][j] = (f32x4)0.f;

#pragma unroll 1
  for (int s = 0; s < 18; ++s) {
    const int o = s >> 1;
    const int dy = o / 3, dx = o - dy * 3;
    const int half = s & 1;
    bf16x8 a[4];
#pragma unroll
    for (int cg = 0; cg < 4; ++cg) {
      const int gi = (cg * 16 + l15) * 72 + s * 4 + oct;
      a[cg] = *(const bf16x8*)(wb + ((gi ^ (l15 & 7)) << 3));
    }
#pragma unroll
    for (int pt = 0; pt < 4; ++pt) {
      const int r = 2 * wv + (pt >> 1) + dy;
      const int cc = (pt & 1) * 16 + dx + l15;
      const int p = r * 34 + cc;
      const int co = ((half * 4 + oct) ^ (cc & 7)) << 3;
      bf16x8 b = *(const bf16x8*)((const short*)Xs + p * 64 + co);
#pragma unroll
      for (int cg = 0; cg < 4; ++cg)
        acc[cg][pt] = __builtin_amdgcn_mfma_f32_16x16x32_bf16(a[cg], b, acc[cg][pt], 0, 0, 0);
    }
  }

  __syncthreads();             // Xs reads done -> reuse as Ys
  u16* Ys = &Xs[0];            // [256 pix][64 ch], XOR swizzle on (p2&7)

  // ---- epilogue 1: x5 = acc + b2 + x(bf16) -> bf16 padded store + Ys ----
#pragma unroll
  for (int cg = 0; cg < 4; ++cg)
#pragma unroll
    for (int pt = 0; pt < 4; ++pt) {
      const int lr = 2 * wv + (pt >> 1);
      const int lc = (pt & 1) * 16 + l15;
      const int p2 = lr * 32 + lc;
      const int pph = h0 + lr + 1, ppw = w0 + lc + 1;
      const int unitg = (cg * 2 + (oct >> 1)) ^ (ppw & 7);
      const size_t gaddr = fbase + ((size_t)pph * PW + ppw) * CH + unitg * 8 + (oct & 1) * 4;
      u16x4 xv = *(const u16x4*)(xp + gaddr);   // residual, same layout as store
      u16x4 pk;
#pragma unroll
      for (int rr = 0; rr < 4; ++rr) {
        const int cout = cg * 16 + oct * 4 + rr;
        float v = acc[cg][pt][rr] + bias[cout] + bf2f(xv[rr]);
        pk[rr] = tobf(v);
      }
      *(u16x4*)(outx + gaddr) = pk;
      const int unit2 = (cg * 2 + (oct >> 1)) ^ (p2 & 7);
      *(u16x4*)(Ys + p2 * 64 + unit2 * 8 + (oct & 1) * 4) = pk;
    }
  __syncthreads();

  // ---- phase 2: k = wk1 @ x5 + bk1 (2 MFMA k-steps) ----
  f32x4 acc2[4][4];
#pragma unroll
  for (int i = 0; i < 4; ++i)
#pragma unroll
    for (int j = 0; j < 4; ++j) acc2[i][j] = (f32x4)0.f;

#pragma unroll
  for (int s = 0; s < 2; ++s) {
    bf16x8 a2[4];
#pragma unroll
    for (int cg = 0; cg < 4; ++cg)
      a2[cg] = *(const bf16x8*)(w1b + (cg * 16 + l15) * 64 + s * 32 + oct * 8);
#pragma unroll
    for (int pt = 0; pt < 4; ++pt) {
      const int p2 = (2 * wv + (pt >> 1)) * 32 + (pt & 1) * 16 + l15;
      const int co = ((s * 4 + oct) ^ (p2 & 7)) << 3;
      bf16x8 b = *(const bf16x8*)((const short*)Ys + p2 * 64 + co);
#pragma unroll
      for (int cg = 0; cg < 4; ++cg)
        acc2[cg][pt] = __builtin_amdgcn_mfma_f32_16x16x32_bf16(a2[cg], b, acc2[cg][pt], 0, 0, 0);
    }
  }

#pragma unroll
  for (int cg = 0; cg < 4; ++cg)
#pragma unroll
    for (int pt = 0; pt < 4; ++pt) {
      const int py = h0 + 2 * wv + (pt >> 1);
      const int px = w0 + (pt & 1) * 16 + l15;
      const int pph = py + 1, ppw = px + 1;
      const int unit = (cg * 2 + (oct >> 1)) ^ (ppw & 7);
      u16x4 pk;
#pragma unroll
      for (int rr = 0; rr < 4; ++rr) {
        const int kout = cg * 16 + oct * 4 + rr;
        pk[rr] = tobf(acc2[cg][pt][rr] + b1x1[kout]);
      }
      *(u16x4*)(outb + ((size_t)f * PW + pph) * PW * CH + (size_t)ppw * CH +
                unit * 8 + (oct & 1) * 4) = pk;
    }
}

// stride-2 3x3 conv 64->9 from padded swizzled bf16. Output (16,9,64,64).
__global__ __launch_bounds__(256) void convs2b_k(
    const u16* __restrict__ inb, const float* __restrict__ wgt,
    const float* __restrict__ bias, float* __restrict__ out)
{
  const int f = blockIdx.y;
  const int idx = blockIdx.x * 256 + threadIdx.x;   // 4096
  const int wo = idx & 63, ho = idx >> 6;
  float acc[9];
#pragma unroll
  for (int i = 0; i < 9; ++i) acc[i] = 0.f;
#pragma unroll 1
  for (int di = 0; di < 3; ++di)
#pragma unroll 1
    for (int dj = 0; dj < 3; ++dj) {
      const int pph = 2 * ho + di, ppw = 2 * wo + dj;
      const u16* row = inb + ((size_t)f * PW + pph) * PW * CH + (size_t)ppw * CH;
      const int q = di * 3 + dj;
#pragma unroll
      for (int ub = 0; ub < 8; ++ub) {
        const int unit = ub ^ (ppw & 7);
        u16x8 pk = *(const u16x8*)(row + unit * 8);
#pragma unroll
        for (int j = 0; j < 8; ++j) {
          const float xv = bf2f(pk[j]);
          const int c = ub * 8 + j;
#pragma unroll
          for (int kk = 0; kk < 9; ++kk)
            acc[kk] = fmaf(xv, wgt[(kk * 64 + c) * 9 + q], acc[kk]);
        }
      }
    }
  const int oBase = f * 9 * 4096 + ho * 64 + wo;
#pragma unroll
  for (int kk = 0; kk < 9; ++kk) out[oBase + kk * 4096] = acc[kk] + bias[kk];
}

// Fused softmax + weighted patch reduce from padded swizzled bf16 x5.
// Loads raw scores, softmaxes 72-vectors in LDS, then channel-vectorized
// gather (u16x8 = 8ch per load, 1KB/wave-instr).
__global__ __launch_bounds__(256) void gather2_k(
    const u16* __restrict__ x5p, const float* __restrict__ sc,
    float* __restrict__ out)
{
  const int hx = blockIdx.x;       // wo half (0..1)
  const int ho = blockIdx.y;       // 0..63
  const int b  = blockIdx.z;       // 0..1
  const int wo0 = hx * 32;
  __shared__ float wl[32 * 73];
  // coalesced score load: lane -> wo, k-major across iterations
  for (int e = threadIdx.x; e < 32 * 72; e += 256) {
    const int wo = e & 31, k = e >> 5;
    const int t = k / 9, kk = k - t * 9;
    wl[wo * 73 + k] = sc[((size_t)((b * 8 + t) * 9 + kk)) * 4096 + ho * 64 + wo0 + wo];
  }
  __syncthreads();
  if (threadIdx.x < 32) {
    float* row = &wl[threadIdx.x * 73];
    float mx = -1e30f;
#pragma unroll
    for (int i = 0; i < 72; ++i) mx = fmaxf(mx, row[i]);
    float sum = 0.f;
#pragma unroll
    for (int i = 0; i < 72; ++i) { float e2 = __expf(row[i] - mx); row[i] = e2; sum += e2; }
    const float inv = 1.f / sum;
#pragma unroll
    for (int i = 0; i < 72; ++i) row[i] *= inv;
  }
  __syncthreads();
  const int lane = threadIdx.x & 63;
  const int wv = threadIdx.x >> 6;
  const int u = lane & 7;                 // channel octet
  const int wol = (lane >> 3) + wv * 8;   // 0..31
  const int wo = wo0 + wol;
  float acc[8];
#pragma unroll
  for (int j = 0; j < 8; ++j) acc[j] = 0.f;
#pragma unroll 1
  for (int t = 0; t < 8; ++t) {
    const int f = b * 8 + t;
    const size_t fb = (size_t)f * PW * PW * CH;
    const float* wrow = &wl[wol * 73 + t * 9];
#pragma unroll
    for (int di = 0; di < 3; ++di) {
      const int pph = min(max(2 * ho + di, 1), 128);
#pragma unroll
      for (int dj = 0; dj < 3; ++dj) {
        const int ppw = min(max(2 * wo + dj, 1), 128);
        const int unit = u ^ (ppw & 7);
        u16x8 pk = *(const u16x8*)(x5p + fb + ((size_t)pph * PW + ppw) * CH + unit * 8);
        const float wq = wrow[di * 3 + dj];
#pragma unroll
        for (int j = 0; j < 8; ++j)
          acc[j] = fmaf(bf2f(pk[j]), wq, acc[j]);
      }
    }
  }
  const int obase = ((b * 64 + u * 8) * 64 + ho) * 64 + wo;
#pragma unroll
  for (int j = 0; j < 8; ++j)
    out[obase + j * 4096] = acc[j];
}

extern "C" void kernel_launch(void* const* d_in, const int* in_sizes, int n_in,
                              void* d_out, int out_size, void* d_ws, size_t ws_size,
                              hipStream_t stream)
{
  const float* x   = (const float*)d_in[0];
  const float* w1  = (const float*)d_in[1];
  const float* b1  = (const float*)d_in[2];
  const float* w2  = (const float*)d_in[3];
  const float* b2  = (const float*)d_in[4];
  const float* wk1 = (const float*)d_in[5];
  const float* bk1 = (const float*)d_in[6];
  const float* wk2 = (const float*)d_in[7];
  const float* bk2 = (const float*)d_in[8];
  const float* wk3 = (const float*)d_in[9];
  const float* bk3 = (const float*)d_in[10];
  float* outp = (float*)d_out;

  const size_t PADB = (size_t)16 * PW * PW * CH * 2;   // 34,611,200 B
  char* ws = (char*)d_ws;
  u16*  P1      = (u16*)ws;                            // x bf16, then kf2
  u16*  P2      = (u16*)(ws + PADB);                   // res1
  u16*  P3      = (u16*)(ws + 2 * PADB);               // k
  u16*  P4      = (u16*)(ws + 3 * PADB);               // x5 bf16
  float* scores = (float*)(ws + 4 * PADB);             // 2.25 MB
  short* Wp1    = (short*)(ws + 4 * PADB + 2359296);
  short* Wp2    = Wp1 + 36864;
  short* Wp4    = Wp2 + 36864;
  short* Wk1b   = Wp4 + 36864;                         // 4096 bf16
  (void)ws_size; (void)in_sizes; (void)n_in; (void)out_size;

  hipFuncSetAttribute((const void*)conv3x3_pers_k,
                      hipFuncAttributeMaxDynamicSharedMemorySize, 161792);

  packw_k<<<dim3(144), 256, 0, stream>>>(w1, Wp1);
  packw_k<<<dim3(144), 256, 0, stream>>>(w2, Wp2);
  packw_k<<<dim3(144), 256, 0, stream>>>(wk2, Wp4);
  packw1_k<<<dim3(16), 256, 0, stream>>>(wk1, Wk1b);

  // x -> padded swizzled bf16 (ring = 0)
  xprep_k<<<dim3(16, PW), 256, 0, stream>>>(x, P1);
  // zero pad rings for res1, k, x5
  padzero_k<<<dim3(17, 16), 256, 0, stream>>>(P2);
  padzero_k<<<dim3(17, 16), 256, 0, stream>>>(P3);
  padzero_k<<<dim3(17, 16), 256, 0, stream>>>(P4);

  // 1: res1 = lrelu(conv(x, w1) + b1)                    -> P2
  conv3x3_pers_k<<<dim3(256), 512, 161792, stream>>>(P1, Wp1, b1, P2);
  // 2: x5 = x + conv(res1*shift(res1), w2) + b2 (bf16)   -> P4;
  //    k = wk1@x5 + bk1 (bf16)                           -> P3
  conv3x3_x5_k<<<dim3(4, 16, 16), 256, 0, stream>>>(P2, Wp2, b2, P1, Wk1b, bk1, P4, P3);
  // 3: kf2 = lrelu(conv(k, wk2) + bk2)                   -> P1 (ring 0 from xprep)
  conv3x3_pers_k<<<dim3(256), 512, 161792, stream>>>(P3, Wp4, bk2, P1);
  // 4: scores = conv_s2(kf2, wk3) + bk3
  convs2b_k<<<dim3(16, 16), 256, 0, stream>>>(P1, wk3, bk3, scores);
  // 5: fused softmax + weighted gather (bf16 x5)
  gather2_k<<<dim3(2, 64, 2), 256, 0, stream>>>(P4, scores, outp);
}